// Round 3
// baseline (400.023 us; speedup 1.0000x reference)
//
#include <hip/hip_runtime.h>
#include <hip/hip_bf16.h>

// DA block (DANet) — Round 20: 2 blocks/CU for k_pam2/k_pbm.
// R19 post-mortem: 2 waves/SIMD from ONE block are barrier-lockstep -> no
// overlap (occupancy 2x, time unchanged). Fix: TI=16, 512-thr blocks, grid
// 512 = 2 independent blocks/CU (4 waves/SIMD), launch_bounds(512,4).
// Total MFMA work unchanged; per-acc fp32 j-order and pass-A merge order
// preserved -> pamT bit-identical to R19. Other kernels unchanged.

#define B_ 2
#define C_ 256
#define N_ 4096
#define QK_ 32

#define TI_ 16     // i-rows per block (pass A & B)
#define TJ_ 128    // j per tile (8 waves x 16)
#define PPB_ 136   // p LDS pitch (bf16) = 272 B (16B-aligned rows)

typedef __hip_bfloat16 bf16;
typedef __attribute__((ext_vector_type(8))) short bf16x8f;   // MFMA A/B frag
typedef __attribute__((ext_vector_type(4))) float f32x4;     // MFMA C/D frag

union bf8pack { bf16 h[8]; int4 v; bf16x8f f; };

// ---- k_qk1: partial Q,K projections over a 64-channel chunk ----
__global__ __launch_bounds__(256) void k_qk1(
    const float* __restrict__ x, const float* __restrict__ wq, const float* __restrict__ wk,
    float* __restrict__ qp, float* __restrict__ kp) {
  int b = blockIdx.z;
  int cg = blockIdx.y;                      // 4 chunks of 64 channels
  int n = blockIdx.x * 256 + threadIdx.x;
  float qa[QK_], ka[QK_];
#pragma unroll
  for (int o = 0; o < QK_; o++) { qa[o] = 0.f; ka[o] = 0.f; }
  const float* xp = x + ((size_t)b * C_ + cg * 64) * N_ + n;
  for (int c = 0; c < 64; c++) {
    float xv = xp[(size_t)c * N_];
    int cc = cg * 64 + c;
#pragma unroll
    for (int o = 0; o < QK_; o++) {
      qa[o] += wq[o * C_ + cc] * xv;   // uniform weight loads -> scalar path
      ka[o] += wk[o * C_ + cc] * xv;
    }
  }
  float4* qo = (float4*)(qp + (((size_t)cg * B_ + b) * N_ + n) * QK_);
  float4* ko = (float4*)(kp + (((size_t)cg * B_ + b) * N_ + n) * QK_);
#pragma unroll
  for (int u = 0; u < 8; u++) {
    qo[u] = make_float4(qa[4 * u], qa[4 * u + 1], qa[4 * u + 2], qa[4 * u + 3]);
    ko[u] = make_float4(ka[4 * u], ka[4 * u + 1], ka[4 * u + 2], ka[4 * u + 3]);
  }
}

// ---- k_qk2 v2: combine partials + bias, emit hi/lo bf16 split arrays ----
__global__ __launch_bounds__(256) void k_qk2(
    const float* __restrict__ qp, const float* __restrict__ kp,
    const float* __restrict__ bq, const float* __restrict__ bk,
    bf16* __restrict__ qhi, bf16* __restrict__ qlo,
    bf16* __restrict__ khi, bf16* __restrict__ klo) {
  int t = blockIdx.x * 256 + threadIdx.x;    // b*N + n
  int b = t >> 12, n = t & (N_ - 1);
  float qa[QK_], ka[QK_];
#pragma unroll
  for (int o = 0; o < QK_; o++) { qa[o] = bq[o]; ka[o] = bk[o]; }
#pragma unroll
  for (int cg = 0; cg < 4; cg++) {
    const float4* qs = (const float4*)(qp + (((size_t)cg * B_ + b) * N_ + n) * QK_);
    const float4* ks = (const float4*)(kp + (((size_t)cg * B_ + b) * N_ + n) * QK_);
#pragma unroll
    for (int u = 0; u < 8; u++) {
      float4 q4 = qs[u], k4 = ks[u];
      qa[4 * u] += q4.x; qa[4 * u + 1] += q4.y; qa[4 * u + 2] += q4.z; qa[4 * u + 3] += q4.w;
      ka[4 * u] += k4.x; ka[4 * u + 1] += k4.y; ka[4 * u + 2] += k4.z; ka[4 * u + 3] += k4.w;
    }
  }
  size_t base = (size_t)t * QK_;
#pragma unroll
  for (int g = 0; g < 4; g++) {
    bf8pack qh, ql, kh, kl;
#pragma unroll
    for (int u = 0; u < 8; u++) {
      float qv = qa[g * 8 + u], kv = ka[g * 8 + u];
      bf16 qhh = __float2bfloat16(qv);
      bf16 khh = __float2bfloat16(kv);
      qh.h[u] = qhh; ql.h[u] = __float2bfloat16(qv - __bfloat162float(qhh));
      kh.h[u] = khh; kl.h[u] = __float2bfloat16(kv - __bfloat162float(khh));
    }
    *(int4*)(qhi + base + g * 8) = qh.v;
    *(int4*)(qlo + base + g * 8) = ql.v;
    *(int4*)(khi + base + g * 8) = kh.v;
    *(int4*)(klo + base + g * 8) = kl.v;
  }
}

// ---- k_vbf: V proj -> vbf[b,c,j] bf16; 8 channels/block ----
__global__ __launch_bounds__(256) void k_vbf(
    const float* __restrict__ x, const float* __restrict__ wv, const float* __restrict__ bv,
    bf16* __restrict__ vbf) {
  int b = blockIdx.z;
  int co0 = blockIdx.y * 8;
  int n0 = blockIdx.x * 256;
  int tid = threadIdx.x;
  float acc[8];
#pragma unroll
  for (int o = 0; o < 8; o++) acc[o] = bv[co0 + o];
  const float* xp = x + (size_t)b * C_ * N_ + n0 + tid;
  for (int c = 0; c < C_; c++) {
    float xv = xp[(size_t)c * N_];
#pragma unroll
    for (int o = 0; o < 8; o++) acc[o] += wv[(co0 + o) * C_ + c] * xv;
  }
#pragma unroll
  for (int o = 0; o < 8; o++)
    vbf[((size_t)b * C_ + co0 + o) * N_ + n0 + tid] = __float2bfloat16(acc[o]);
}

// ---- k_pam2 v4: 8-wave, TI=16, 2 blocks/CU — online (m,l) per row ----
__global__ __launch_bounds__(512, 4) void k_pam2(
    const bf16* __restrict__ qhi, const bf16* __restrict__ qlo,
    const bf16* __restrict__ khi, const bf16* __restrict__ klo,
    float* __restrict__ mrow, float* __restrict__ lrowi) {
  int b = blockIdx.y;
  int i0 = blockIdx.x * TI_;
  int tid = threadIdx.x;
  int lane = tid & 63, wave = tid >> 6;          // wave 0..7
  int n16 = lane & 15, quad = lane >> 4;

  __shared__ float red_m[8 * 16], red_l[8 * 16];

  bf16x8f ahf, alf;
  {
    size_t qoff = ((size_t)b * N_ + i0 + n16) * QK_ + quad * 8;
    ahf = *(const bf16x8f*)(const void*)(qhi + qoff);
    alf = *(const bf16x8f*)(const void*)(qlo + qoff);
  }

  float m4[4], l4[4];
#pragma unroll
  for (int k = 0; k < 4; k++) { m4[k] = -3.0e38f; l4[k] = 0.f; }

  const bf16* khb = khi + ((size_t)b * N_ + wave * 16 + n16) * QK_ + quad * 8;
  const bf16* klb = klo + ((size_t)b * N_ + wave * 16 + n16) * QK_ + quad * 8;
  bf16x8f khf = *(const bf16x8f*)(const void*)khb;
  bf16x8f klf = *(const bf16x8f*)(const void*)klb;

  for (int jt = 0; jt < N_ / TJ_; jt++) {        // 32 iterations
    bf16x8f khn, kln;
    if (jt + 1 < N_ / TJ_) {
      size_t off = (size_t)(jt + 1) * TJ_ * QK_;
      khn = *(const bf16x8f*)(const void*)(khb + off);
      kln = *(const bf16x8f*)(const void*)(klb + off);
    }
    f32x4 z = (f32x4)(0.f);
    z = __builtin_amdgcn_mfma_f32_16x16x32_bf16(ahf, khf, z, 0, 0, 0);
    z = __builtin_amdgcn_mfma_f32_16x16x32_bf16(alf, khf, z, 0, 0, 0);
    z = __builtin_amdgcn_mfma_f32_16x16x32_bf16(ahf, klf, z, 0, 0, 0);
#pragma unroll
    for (int r = 0; r < 4; r++) {
      float sv = z[r];
      float nm = fmaxf(m4[r], sv);
      l4[r] = l4[r] * __expf(m4[r] - nm) + __expf(sv - nm);
      m4[r] = nm;
    }
    khf = khn; klf = kln;
  }
#pragma unroll
  for (int d = 1; d < 16; d <<= 1) {
#pragma unroll
    for (int k = 0; k < 4; k++) {
      float om = __shfl_xor(m4[k], d, 64);
      float ol = __shfl_xor(l4[k], d, 64);
      float nm = fmaxf(m4[k], om);
      l4[k] = l4[k] * __expf(m4[k] - nm) + ol * __expf(om - nm);
      m4[k] = nm;
    }
  }
  if (n16 == 0) {
#pragma unroll
    for (int r = 0; r < 4; r++) {
      int i = quad * 4 + r;
      red_m[wave * 16 + i] = m4[r];
      red_l[wave * 16 + i] = l4[r];
    }
  }
  __syncthreads();
  if (tid < 16) {
    float wm[8];
    float M = -3.0e38f;
#pragma unroll
    for (int w = 0; w < 8; w++) { wm[w] = red_m[w * 16 + tid]; M = fmaxf(M, wm[w]); }
    float L = 0.f;
#pragma unroll
    for (int w = 0; w < 8; w++) L += red_l[w * 16 + tid] * __expf(wm[w] - M);
    mrow[b * N_ + i0 + tid] = M;
    lrowi[b * N_ + i0 + tid] = 1.0f / L;
  }
}

// ---- k_pbm v7: 8-wave, TI=16, 2 blocks/CU — pamT[b,i,c] = sum_j P V ----
// Wave owns 16-j slice for P, 32 channels for PV. Same j-order per acc.
__global__ __launch_bounds__(512, 4) void k_pbm(
    const bf16* __restrict__ qhi, const bf16* __restrict__ qlo,
    const bf16* __restrict__ khi, const bf16* __restrict__ klo,
    const bf16* __restrict__ vbf,
    const float* __restrict__ mrow, const float* __restrict__ lrowi,
    float* __restrict__ pamT) {
  int b = blockIdx.y;
  int i0 = blockIdx.x * TI_;
  int tid = threadIdx.x;
  int lane = tid & 63, wave = tid >> 6;          // wave 0..7
  int n16 = lane & 15, quad = lane >> 4;

  __shared__ __align__(16) bf16 p_s[2][TI_ * PPB_];   // 8.7 KB double-buffered

  float mreg[4], lireg[4];
#pragma unroll
  for (int r = 0; r < 4; r++) {
    int i = quad * 4 + r;
    mreg[r] = mrow[b * N_ + i0 + i];
    lireg[r] = lrowi[b * N_ + i0 + i];
  }

  bf16x8f ahf, alf;
  {
    size_t qoff = ((size_t)b * N_ + i0 + n16) * QK_ + quad * 8;
    ahf = *(const bf16x8f*)(const void*)(qhi + qoff);
    alf = *(const bf16x8f*)(const void*)(qlo + qoff);
  }

  f32x4 acc[2];                                  // [cb], 32 ch/wave
#pragma unroll
  for (int cb = 0; cb < 2; cb++) acc[cb] = (f32x4)(0.f);

  const bf16* khb = khi + ((size_t)b * N_ + wave * 16 + n16) * QK_ + quad * 8;
  const bf16* klb = klo + ((size_t)b * N_ + wave * 16 + n16) * QK_ + quad * 8;
  const bf16* vb0 = vbf + ((size_t)b * C_ + wave * 32 + n16) * N_ + quad * 8;

  bf16x8f khf = *(const bf16x8f*)(const void*)khb;
  bf16x8f klf = *(const bf16x8f*)(const void*)klb;
  bf16x8f vcur[2][4];
#pragma unroll
  for (int cb = 0; cb < 2; cb++)
#pragma unroll
    for (int h = 0; h < 4; h++)
      vcur[cb][h] = *(const bf16x8f*)(const void*)(vb0 + (size_t)cb * 16 * N_ + h * 32);

  for (int jt = 0; jt < N_ / TJ_; jt++) {        // 32 iterations
    bf16x8f khn, kln, vnxt[2][4];
    if (jt + 1 < N_ / TJ_) {
      size_t koff = (size_t)(jt + 1) * TJ_ * QK_;
      khn = *(const bf16x8f*)(const void*)(khb + koff);
      kln = *(const bf16x8f*)(const void*)(klb + koff);
      int jb = (jt + 1) * TJ_;
#pragma unroll
      for (int cb = 0; cb < 2; cb++)
#pragma unroll
        for (int h = 0; h < 4; h++)
          vnxt[cb][h] = *(const bf16x8f*)(const void*)(vb0 + (size_t)cb * 16 * N_ + jb + h * 32);
    }
    f32x4 z = (f32x4)(0.f);
    z = __builtin_amdgcn_mfma_f32_16x16x32_bf16(ahf, khf, z, 0, 0, 0);
    z = __builtin_amdgcn_mfma_f32_16x16x32_bf16(alf, khf, z, 0, 0, 0);
    z = __builtin_amdgcn_mfma_f32_16x16x32_bf16(ahf, klf, z, 0, 0, 0);

    bf16* pbuf = p_s[jt & 1];
#pragma unroll
    for (int r = 0; r < 4; r++) {
      int i = quad * 4 + r;
      float p = __expf(z[r] - mreg[r]) * lireg[r];
      pbuf[i * PPB_ + wave * 16 + n16] = __float2bfloat16(p);
    }
    __syncthreads();   // the ONE barrier per iter (double-buffered p_s)
    bf16x8f pa[4];
#pragma unroll
    for (int jh = 0; jh < 4; jh++)
      pa[jh] = *(const bf16x8f*)(const void*)(pbuf + n16 * PPB_ + jh * 32 + quad * 8);
#pragma unroll
    for (int cb = 0; cb < 2; cb++) {
#pragma unroll
      for (int jh = 0; jh < 4; jh++)
        acc[cb] = __builtin_amdgcn_mfma_f32_16x16x32_bf16(pa[jh], vcur[cb][jh], acc[cb], 0, 0, 0);
    }
    khf = khn; klf = kln;
#pragma unroll
    for (int cb = 0; cb < 2; cb++)
#pragma unroll
      for (int h = 0; h < 4; h++) vcur[cb][h] = vnxt[cb][h];
  }
#pragma unroll
  for (int cb = 0; cb < 2; cb++) {
    int c = wave * 32 + cb * 16 + n16;
#pragma unroll
    for (int r = 0; r < 4; r++) {
      int i = quad * 4 + r;
      pamT[((size_t)b * N_ + i0 + i) * C_ + c] = acc[cb][r];
    }
  }
}

// ---- k_ce: CAM energy partials over K-chunks ----
__global__ __launch_bounds__(256) void k_ce(const float* __restrict__ x, float* __restrict__ eCp) {
  int b = blockIdx.z;
  int kc = blockIdx.y;
  int it = blockIdx.x & 7, jt = blockIdx.x >> 3;
  int i0 = it * 32, j0 = jt * 32;
  __shared__ float xi[32 * 65], xj[32 * 65];
  int tid = threadIdx.x;
  int ti2 = (tid & 15) * 2, tj2 = (tid >> 4) * 2;
  float a00 = 0.f, a01 = 0.f, a10 = 0.f, a11 = 0.f;
  for (int n0 = 0; n0 < 512; n0 += 64) {
    __syncthreads();
#pragma unroll
    for (int k = 0; k < 8; k++) {
      int e = k * 256 + tid;
      int r = e >> 6, c = e & 63;
      xi[r * 65 + c] = x[((size_t)b * C_ + i0 + r) * N_ + kc * 512 + n0 + c];
      xj[r * 65 + c] = x[((size_t)b * C_ + j0 + r) * N_ + kc * 512 + n0 + c];
    }
    __syncthreads();
#pragma unroll 4
    for (int n = 0; n < 64; n++) {
      float u0 = xi[ti2 * 65 + n], u1 = xi[(ti2 + 1) * 65 + n];
      float w0 = xj[tj2 * 65 + n], w1 = xj[(tj2 + 1) * 65 + n];
      a00 += u0 * w0; a01 += u0 * w1; a10 += u1 * w0; a11 += u1 * w1;
    }
  }
  float* dst = eCp + (((size_t)kc * B_ + b) * C_ + i0) * C_ + j0;
  dst[(ti2 + 0) * C_ + tj2 + 0] = a00;
  dst[(ti2 + 0) * C_ + tj2 + 1] = a01;
  dst[(ti2 + 1) * C_ + tj2 + 0] = a10;
  dst[(ti2 + 1) * C_ + tj2 + 1] = a11;
}

// ---- k_cs: CAM softmax over -e ----
__global__ __launch_bounds__(256) void k_cs(const float* __restrict__ eCp, float* __restrict__ attnC) {
  int row = blockIdx.x;
  int b = row >> 8, i = row & 255;
  int j = threadIdx.x;
  float e = 0.f;
#pragma unroll
  for (int kc = 0; kc < 8; kc++) e += eCp[(((size_t)kc * B_ + b) * C_ + i) * C_ + j];
  float ne = -e;
  __shared__ float buf[256];
  buf[j] = ne;
  __syncthreads();
  for (int st = 128; st >= 1; st >>= 1) {
    if (j < st) buf[j] = fmaxf(buf[j], buf[j + st]);
    __syncthreads();
  }
  float m = buf[0];
  __syncthreads();
  float p = __expf(ne - m);
  buf[j] = p;
  __syncthreads();
  for (int st = 128; st >= 1; st >>= 1) {
    if (j < st) buf[j] += buf[j + st];
    __syncthreads();
  }
  attnC[(size_t)row * C_ + j] = p / buf[0];
}

// ---- k_co v2: CAM out + combine; 16 ch/block, j-unroll x8 hoisted loads ----
__global__ __launch_bounds__(256) void k_co(
    const float* __restrict__ x, const float* __restrict__ attnC, const float* __restrict__ pamT,
    const float* __restrict__ gpam, const float* __restrict__ gcam, float* __restrict__ out) {
  int b = blockIdx.z, c0 = blockIdx.y * 16, n0 = blockIdx.x * 256;
  int tid = threadIdx.x;
  __shared__ float pam_s[256 * 17];
#pragma unroll
  for (int k = 0; k < 16; k++) {
    int e = k * 256 + tid;
    int r = e >> 4, cc = e & 15;
    pam_s[r * 17 + cc] = pamT[((size_t)b * N_ + n0 + r) * C_ + c0 + cc];
  }
  __syncthreads();
  float acc[16];
#pragma unroll
  for (int i = 0; i < 16; i++) acc[i] = 0.f;
  const float* arow = attnC + ((size_t)b * C_ + c0) * C_;
  for (int j0 = 0; j0 < C_; j0 += 8) {
    float xv[8];
#pragma unroll
    for (int u = 0; u < 8; u++)          // 8 independent loads in flight
      xv[u] = x[((size_t)b * C_ + j0 + u) * N_ + n0 + tid];
#pragma unroll
    for (int i = 0; i < 16; i++)
#pragma unroll
      for (int u = 0; u < 8; u++)        // ascending j per acc[i] -> same order
        acc[i] += arow[i * C_ + j0 + u] * xv[u];
  }
  float gp = gpam[0], gc = gcam[0];
#pragma unroll
  for (int i = 0; i < 16; i++) {
    size_t idx = ((size_t)b * C_ + c0 + i) * N_ + n0 + tid;
    out[idx] = gp * pam_s[tid * 17 + i] + gc * acc[i] + 2.0f * x[idx];
  }
}

extern "C" void kernel_launch(void* const* d_in, const int* in_sizes, int n_in,
                              void* d_out, int out_size, void* d_ws, size_t ws_size,
                              hipStream_t stream) {
  const float* x  = (const float*)d_in[0];
  const float* wq = (const float*)d_in[1];
  const float* bq = (const float*)d_in[2];
  const float* wk = (const float*)d_in[3];
  const float* bk = (const float*)d_in[4];
  const float* wv = (const float*)d_in[5];
  const float* bv = (const float*)d_in[6];
  const float* gp = (const float*)d_in[7];
  const float* gc = (const float*)d_in[8];
  float* out = (float*)d_out;

  float* ws = (float*)d_ws;
  size_t o = 0;
  float* pamT  = ws + o; o += (size_t)B_ * N_ * C_;     // 2097152
  float* mrow  = ws + o; o += (size_t)B_ * N_;          // 8192
  float* lrowi = ws + o; o += (size_t)B_ * N_;          // 8192
  float* eCp   = ws + o; o += (size_t)8 * B_ * C_ * C_; // 1048576
  float* attnC = ws + o; o += (size_t)B_ * C_ * C_;     // 131072
  bf16*  vbf   = (bf16*)(ws + o); o += (size_t)B_ * N_ * C_ / 2;   // 1048576
  bf16*  qhi   = (bf16*)(ws + o); o += (size_t)B_ * N_ * QK_ / 2;  // 131072
  bf16*  qlo   = (bf16*)(ws + o); o += (size_t)B_ * N_ * QK_ / 2;  // 131072
  bf16*  khi   = (bf16*)(ws + o); o += (size_t)B_ * N_ * QK_ / 2;  // 131072
  bf16*  klo   = (bf16*)(ws + o); o += (size_t)B_ * N_ * QK_ / 2;  // 131072
  float* qpprt = ws + o; o += (size_t)4 * B_ * N_ * QK_; // 1048576
  float* kpprt = ws + o; o += (size_t)4 * B_ * N_ * QK_; // 1048576
  // total ~6.8 M floats = 27.3 MB

  k_qk1<<<dim3(16, 4, B_), dim3(256), 0, stream>>>(x, wq, wk, qpprt, kpprt);
  k_qk2<<<dim3(32), dim3(256), 0, stream>>>(qpprt, kpprt, bq, bk, qhi, qlo, khi, klo);
  k_vbf<<<dim3(16, 32, B_), dim3(256), 0, stream>>>(x, wv, bv, vbf);
  k_pam2<<<dim3(N_ / TI_, B_), dim3(512), 0, stream>>>(qhi, qlo, khi, klo, mrow, lrowi);
  k_pbm<<<dim3(N_ / TI_, B_), dim3(512), 0, stream>>>(qhi, qlo, khi, klo, vbf, mrow, lrowi, pamT);
  k_ce<<<dim3(64, 8, B_), dim3(256), 0, stream>>>(x, eCp);
  k_cs<<<dim3(B_ * C_), dim3(256), 0, stream>>>(eCp, attnC);
  k_co<<<dim3(16, 16, B_), dim3(256), 0, stream>>>(x, attnC, pamT, gp, gc, out);
}

// Round 4
// 319.369 us; speedup vs baseline: 1.2525x; 1.2525x over previous
//
#include <hip/hip_runtime.h>
#include <hip/hip_bf16.h>

// DA block (DANet) — Round 21: traffic-amortized k_pam2/k_pbm.
// R18/R19/R20 fit: time ∝ per-CU vector-load volume (L1/L2 fill path bound).
// k_pbm: TI=64 rows, 128-ch half-blocks -> 192 B/output (was 320). Grid 256.
// k_pam2: TI=64 rows, j-split in halves (grid 256); partial (m,l) merged
// exactly in k_pbm's prologue. Other kernels identical to R19-green.

#define B_ 2
#define C_ 256
#define N_ 4096
#define QK_ 32

#define TJ_ 128    // j per tile (8 waves x 16)
#define PPB_ 136   // p LDS pitch (bf16) = 272 B (16B-aligned rows)

typedef __hip_bfloat16 bf16;
typedef __attribute__((ext_vector_type(8))) short bf16x8f;   // MFMA A/B frag
typedef __attribute__((ext_vector_type(4))) float f32x4;     // MFMA C/D frag

union bf8pack { bf16 h[8]; int4 v; bf16x8f f; };

// ---- k_qk1: partial Q,K projections over a 64-channel chunk ----
__global__ __launch_bounds__(256) void k_qk1(
    const float* __restrict__ x, const float* __restrict__ wq, const float* __restrict__ wk,
    float* __restrict__ qp, float* __restrict__ kp) {
  int b = blockIdx.z;
  int cg = blockIdx.y;                      // 4 chunks of 64 channels
  int n = blockIdx.x * 256 + threadIdx.x;
  float qa[QK_], ka[QK_];
#pragma unroll
  for (int o = 0; o < QK_; o++) { qa[o] = 0.f; ka[o] = 0.f; }
  const float* xp = x + ((size_t)b * C_ + cg * 64) * N_ + n;
  for (int c = 0; c < 64; c++) {
    float xv = xp[(size_t)c * N_];
    int cc = cg * 64 + c;
#pragma unroll
    for (int o = 0; o < QK_; o++) {
      qa[o] += wq[o * C_ + cc] * xv;   // uniform weight loads -> scalar path
      ka[o] += wk[o * C_ + cc] * xv;
    }
  }
  float4* qo = (float4*)(qp + (((size_t)cg * B_ + b) * N_ + n) * QK_);
  float4* ko = (float4*)(kp + (((size_t)cg * B_ + b) * N_ + n) * QK_);
#pragma unroll
  for (int u = 0; u < 8; u++) {
    qo[u] = make_float4(qa[4 * u], qa[4 * u + 1], qa[4 * u + 2], qa[4 * u + 3]);
    ko[u] = make_float4(ka[4 * u], ka[4 * u + 1], ka[4 * u + 2], ka[4 * u + 3]);
  }
}

// ---- k_qk2 v2: combine partials + bias, emit hi/lo bf16 split arrays ----
__global__ __launch_bounds__(256) void k_qk2(
    const float* __restrict__ qp, const float* __restrict__ kp,
    const float* __restrict__ bq, const float* __restrict__ bk,
    bf16* __restrict__ qhi, bf16* __restrict__ qlo,
    bf16* __restrict__ khi, bf16* __restrict__ klo) {
  int t = blockIdx.x * 256 + threadIdx.x;    // b*N + n
  int b = t >> 12, n = t & (N_ - 1);
  float qa[QK_], ka[QK_];
#pragma unroll
  for (int o = 0; o < QK_; o++) { qa[o] = bq[o]; ka[o] = bk[o]; }
#pragma unroll
  for (int cg = 0; cg < 4; cg++) {
    const float4* qs = (const float4*)(qp + (((size_t)cg * B_ + b) * N_ + n) * QK_);
    const float4* ks = (const float4*)(kp + (((size_t)cg * B_ + b) * N_ + n) * QK_);
#pragma unroll
    for (int u = 0; u < 8; u++) {
      float4 q4 = qs[u], k4 = ks[u];
      qa[4 * u] += q4.x; qa[4 * u + 1] += q4.y; qa[4 * u + 2] += q4.z; qa[4 * u + 3] += q4.w;
      ka[4 * u] += k4.x; ka[4 * u + 1] += k4.y; ka[4 * u + 2] += k4.z; ka[4 * u + 3] += k4.w;
    }
  }
  size_t base = (size_t)t * QK_;
#pragma unroll
  for (int g = 0; g < 4; g++) {
    bf8pack qh, ql, kh, kl;
#pragma unroll
    for (int u = 0; u < 8; u++) {
      float qv = qa[g * 8 + u], kv = ka[g * 8 + u];
      bf16 qhh = __float2bfloat16(qv);
      bf16 khh = __float2bfloat16(kv);
      qh.h[u] = qhh; ql.h[u] = __float2bfloat16(qv - __bfloat162float(qhh));
      kh.h[u] = khh; kl.h[u] = __float2bfloat16(kv - __bfloat162float(khh));
    }
    *(int4*)(qhi + base + g * 8) = qh.v;
    *(int4*)(qlo + base + g * 8) = ql.v;
    *(int4*)(khi + base + g * 8) = kh.v;
    *(int4*)(klo + base + g * 8) = kl.v;
  }
}

// ---- k_vbf: V proj -> vbf[b,c,j] bf16; 8 channels/block ----
__global__ __launch_bounds__(256) void k_vbf(
    const float* __restrict__ x, const float* __restrict__ wv, const float* __restrict__ bv,
    bf16* __restrict__ vbf) {
  int b = blockIdx.z;
  int co0 = blockIdx.y * 8;
  int n0 = blockIdx.x * 256;
  int tid = threadIdx.x;
  float acc[8];
#pragma unroll
  for (int o = 0; o < 8; o++) acc[o] = bv[co0 + o];
  const float* xp = x + (size_t)b * C_ * N_ + n0 + tid;
  for (int c = 0; c < C_; c++) {
    float xv = xp[(size_t)c * N_];
#pragma unroll
    for (int o = 0; o < 8; o++) acc[o] += wv[(co0 + o) * C_ + c] * xv;
  }
#pragma unroll
  for (int o = 0; o < 8; o++)
    vbf[((size_t)b * C_ + co0 + o) * N_ + n0 + tid] = __float2bfloat16(acc[o]);
}

// ---- k_pam2 v5: TI=64, j-half split. Partial (m,l) per half ----
// grid (N/64, 2, B); 8 waves, wave = 16-j slice of a 128-j tile.
__global__ __launch_bounds__(512) void k_pam2(
    const bf16* __restrict__ qhi, const bf16* __restrict__ qlo,
    const bf16* __restrict__ khi, const bf16* __restrict__ klo,
    float* __restrict__ mp, float* __restrict__ lp) {
  int b = blockIdx.z;
  int jhalf = blockIdx.y;
  size_t j0 = (size_t)jhalf * (N_ / 2);
  int i0 = blockIdx.x * 64;
  int tid = threadIdx.x;
  int lane = tid & 63, wave = tid >> 6;
  int n16 = lane & 15, quad = lane >> 4;

  __shared__ float red_m[8 * 64], red_l[8 * 64];

  bf16x8f ahf[4], alf[4];
#pragma unroll
  for (int ih = 0; ih < 4; ih++) {
    size_t qoff = ((size_t)b * N_ + i0 + ih * 16 + n16) * QK_ + quad * 8;
    ahf[ih] = *(const bf16x8f*)(const void*)(qhi + qoff);
    alf[ih] = *(const bf16x8f*)(const void*)(qlo + qoff);
  }

  float m16[16], l16[16];
#pragma unroll
  for (int k = 0; k < 16; k++) { m16[k] = -3.0e38f; l16[k] = 0.f; }

  const bf16* khb = khi + ((size_t)b * N_ + j0 + wave * 16 + n16) * QK_ + quad * 8;
  const bf16* klb = klo + ((size_t)b * N_ + j0 + wave * 16 + n16) * QK_ + quad * 8;
  bf16x8f khf = *(const bf16x8f*)(const void*)khb;
  bf16x8f klf = *(const bf16x8f*)(const void*)klb;

  const int NJT = (N_ / 2) / TJ_;                // 16 iterations
  for (int jt = 0; jt < NJT; jt++) {
    bf16x8f khn, kln;
    if (jt + 1 < NJT) {
      size_t off = (size_t)(jt + 1) * TJ_ * QK_;
      khn = *(const bf16x8f*)(const void*)(khb + off);
      kln = *(const bf16x8f*)(const void*)(klb + off);
    }
#pragma unroll
    for (int ih = 0; ih < 4; ih++) {
      f32x4 z = (f32x4)(0.f);
      z = __builtin_amdgcn_mfma_f32_16x16x32_bf16(ahf[ih], khf, z, 0, 0, 0);
      z = __builtin_amdgcn_mfma_f32_16x16x32_bf16(alf[ih], khf, z, 0, 0, 0);
      z = __builtin_amdgcn_mfma_f32_16x16x32_bf16(ahf[ih], klf, z, 0, 0, 0);
#pragma unroll
      for (int r = 0; r < 4; r++) {
        int k = ih * 4 + r;
        float sv = z[r];
        float nm = fmaxf(m16[k], sv);
        l16[k] = l16[k] * __expf(m16[k] - nm) + __expf(sv - nm);
        m16[k] = nm;
      }
    }
    khf = khn; klf = kln;
  }
#pragma unroll
  for (int d = 1; d < 16; d <<= 1) {
#pragma unroll
    for (int k = 0; k < 16; k++) {
      float om = __shfl_xor(m16[k], d, 64);
      float ol = __shfl_xor(l16[k], d, 64);
      float nm = fmaxf(m16[k], om);
      l16[k] = l16[k] * __expf(m16[k] - nm) + ol * __expf(om - nm);
      m16[k] = nm;
    }
  }
  if (n16 == 0) {
#pragma unroll
    for (int ih = 0; ih < 4; ih++)
#pragma unroll
      for (int r = 0; r < 4; r++) {
        int i = ih * 16 + quad * 4 + r;
        red_m[wave * 64 + i] = m16[ih * 4 + r];
        red_l[wave * 64 + i] = l16[ih * 4 + r];
      }
  }
  __syncthreads();
  if (tid < 64) {
    float wm[8];
    float M = -3.0e38f;
#pragma unroll
    for (int w = 0; w < 8; w++) { wm[w] = red_m[w * 64 + tid]; M = fmaxf(M, wm[w]); }
    float L = 0.f;
#pragma unroll
    for (int w = 0; w < 8; w++) L += red_l[w * 64 + tid] * __expf(wm[w] - M);
    mp[((size_t)jhalf * B_ + b) * N_ + i0 + tid] = M;
    lp[((size_t)jhalf * B_ + b) * N_ + i0 + tid] = L;
  }
}

// ---- k_pbm v8: TI=64 rows x 128-ch half per block; grid (N/64, 2, B) ----
// Wave: 16-j slice for P production; 16 channels for PV. 28 MFMA/barrier.
// Per-block traffic: K 512KB + V 1MB = 192 B/output (R19: 320).
__global__ __launch_bounds__(512) void k_pbm(
    const bf16* __restrict__ qhi, const bf16* __restrict__ qlo,
    const bf16* __restrict__ khi, const bf16* __restrict__ klo,
    const bf16* __restrict__ vbf,
    const float* __restrict__ mp, const float* __restrict__ lp,
    float* __restrict__ pamT) {
  int b = blockIdx.z;
  int h0 = blockIdx.y * 128;                     // channel half
  int i0 = blockIdx.x * 64;
  int tid = threadIdx.x;
  int lane = tid & 63, wave = tid >> 6;
  int n16 = lane & 15, quad = lane >> 4;

  __shared__ __align__(16) bf16 p_s[2][64 * PPB_];   // 34.8 KB double-buffered

  // merge the two j-half (m,l) partials exactly
  float mreg[16], lireg[16];
#pragma unroll
  for (int ih = 0; ih < 4; ih++)
#pragma unroll
    for (int r = 0; r < 4; r++) {
      int i = i0 + ih * 16 + quad * 4 + r;
      float m0 = mp[(size_t)b * N_ + i],          l0 = lp[(size_t)b * N_ + i];
      float m1 = mp[((size_t)B_ + b) * N_ + i],   l1 = lp[((size_t)B_ + b) * N_ + i];
      float M = fmaxf(m0, m1);
      mreg[ih * 4 + r] = M;
      lireg[ih * 4 + r] = 1.0f / (l0 * __expf(m0 - M) + l1 * __expf(m1 - M));
    }

  bf16x8f ahf[4], alf[4];
#pragma unroll
  for (int ih = 0; ih < 4; ih++) {
    size_t qoff = ((size_t)b * N_ + i0 + ih * 16 + n16) * QK_ + quad * 8;
    ahf[ih] = *(const bf16x8f*)(const void*)(qhi + qoff);
    alf[ih] = *(const bf16x8f*)(const void*)(qlo + qoff);
  }

  f32x4 acc[4];                                  // [ih], 16 ch/wave
#pragma unroll
  for (int ih = 0; ih < 4; ih++) acc[ih] = (f32x4)(0.f);

  const bf16* khb = khi + ((size_t)b * N_ + wave * 16 + n16) * QK_ + quad * 8;
  const bf16* klb = klo + ((size_t)b * N_ + wave * 16 + n16) * QK_ + quad * 8;
  const bf16* vb0 = vbf + ((size_t)b * C_ + h0 + wave * 16 + n16) * N_ + quad * 8;

  bf16x8f khf = *(const bf16x8f*)(const void*)khb;
  bf16x8f klf = *(const bf16x8f*)(const void*)klb;
  bf16x8f vcur[4];
#pragma unroll
  for (int jh = 0; jh < 4; jh++)
    vcur[jh] = *(const bf16x8f*)(const void*)(vb0 + jh * 32);

  for (int jt = 0; jt < N_ / TJ_; jt++) {        // 32 iterations
    bf16x8f khn, kln, vnxt[4];
    if (jt + 1 < N_ / TJ_) {
      size_t koff = (size_t)(jt + 1) * TJ_ * QK_;
      khn = *(const bf16x8f*)(const void*)(khb + koff);
      kln = *(const bf16x8f*)(const void*)(klb + koff);
      int jb = (jt + 1) * TJ_;
#pragma unroll
      for (int jh = 0; jh < 4; jh++)
        vnxt[jh] = *(const bf16x8f*)(const void*)(vb0 + jb + jh * 32);
    }
    bf16* pbuf = p_s[jt & 1];
#pragma unroll
    for (int ih = 0; ih < 4; ih++) {
      f32x4 z = (f32x4)(0.f);
      z = __builtin_amdgcn_mfma_f32_16x16x32_bf16(ahf[ih], khf, z, 0, 0, 0);
      z = __builtin_amdgcn_mfma_f32_16x16x32_bf16(alf[ih], khf, z, 0, 0, 0);
      z = __builtin_amdgcn_mfma_f32_16x16x32_bf16(ahf[ih], klf, z, 0, 0, 0);
#pragma unroll
      for (int r = 0; r < 4; r++) {
        int i = ih * 16 + quad * 4 + r;
        float p = __expf(z[r] - mreg[ih * 4 + r]) * lireg[ih * 4 + r];
        pbuf[i * PPB_ + wave * 16 + n16] = __float2bfloat16(p);
      }
    }
    __syncthreads();   // the ONE barrier per iter (double-buffered p_s)
#pragma unroll
    for (int jh = 0; jh < 4; jh++) {
      bf16x8f pa[4];
#pragma unroll
      for (int ih = 0; ih < 4; ih++)
        pa[ih] = *(const bf16x8f*)(const void*)(pbuf + (ih * 16 + n16) * PPB_ + jh * 32 + quad * 8);
#pragma unroll
      for (int ih = 0; ih < 4; ih++)
        acc[ih] = __builtin_amdgcn_mfma_f32_16x16x32_bf16(pa[ih], vcur[jh], acc[ih], 0, 0, 0);
    }
    khf = khn; klf = kln;
#pragma unroll
    for (int jh = 0; jh < 4; jh++) vcur[jh] = vnxt[jh];
  }
  int c = h0 + wave * 16 + n16;
#pragma unroll
  for (int ih = 0; ih < 4; ih++)
#pragma unroll
    for (int r = 0; r < 4; r++) {
      int i = ih * 16 + quad * 4 + r;
      pamT[((size_t)b * N_ + i0 + i) * C_ + c] = acc[ih][r];
    }
}

// ---- k_ce: CAM energy partials over K-chunks ----
__global__ __launch_bounds__(256) void k_ce(const float* __restrict__ x, float* __restrict__ eCp) {
  int b = blockIdx.z;
  int kc = blockIdx.y;
  int it = blockIdx.x & 7, jt = blockIdx.x >> 3;
  int i0 = it * 32, j0 = jt * 32;
  __shared__ float xi[32 * 65], xj[32 * 65];
  int tid = threadIdx.x;
  int ti2 = (tid & 15) * 2, tj2 = (tid >> 4) * 2;
  float a00 = 0.f, a01 = 0.f, a10 = 0.f, a11 = 0.f;
  for (int n0 = 0; n0 < 512; n0 += 64) {
    __syncthreads();
#pragma unroll
    for (int k = 0; k < 8; k++) {
      int e = k * 256 + tid;
      int r = e >> 6, c = e & 63;
      xi[r * 65 + c] = x[((size_t)b * C_ + i0 + r) * N_ + kc * 512 + n0 + c];
      xj[r * 65 + c] = x[((size_t)b * C_ + j0 + r) * N_ + kc * 512 + n0 + c];
    }
    __syncthreads();
#pragma unroll 4
    for (int n = 0; n < 64; n++) {
      float u0 = xi[ti2 * 65 + n], u1 = xi[(ti2 + 1) * 65 + n];
      float w0 = xj[tj2 * 65 + n], w1 = xj[(tj2 + 1) * 65 + n];
      a00 += u0 * w0; a01 += u0 * w1; a10 += u1 * w0; a11 += u1 * w1;
    }
  }
  float* dst = eCp + (((size_t)kc * B_ + b) * C_ + i0) * C_ + j0;
  dst[(ti2 + 0) * C_ + tj2 + 0] = a00;
  dst[(ti2 + 0) * C_ + tj2 + 1] = a01;
  dst[(ti2 + 1) * C_ + tj2 + 0] = a10;
  dst[(ti2 + 1) * C_ + tj2 + 1] = a11;
}

// ---- k_cs: CAM softmax over -e ----
__global__ __launch_bounds__(256) void k_cs(const float* __restrict__ eCp, float* __restrict__ attnC) {
  int row = blockIdx.x;
  int b = row >> 8, i = row & 255;
  int j = threadIdx.x;
  float e = 0.f;
#pragma unroll
  for (int kc = 0; kc < 8; kc++) e += eCp[(((size_t)kc * B_ + b) * C_ + i) * C_ + j];
  float ne = -e;
  __shared__ float buf[256];
  buf[j] = ne;
  __syncthreads();
  for (int st = 128; st >= 1; st >>= 1) {
    if (j < st) buf[j] = fmaxf(buf[j], buf[j + st]);
    __syncthreads();
  }
  float m = buf[0];
  __syncthreads();
  float p = __expf(ne - m);
  buf[j] = p;
  __syncthreads();
  for (int st = 128; st >= 1; st >>= 1) {
    if (j < st) buf[j] += buf[j + st];
    __syncthreads();
  }
  attnC[(size_t)row * C_ + j] = p / buf[0];
}

// ---- k_co v2: CAM out + combine; 16 ch/block, j-unroll x8 hoisted loads ----
__global__ __launch_bounds__(256) void k_co(
    const float* __restrict__ x, const float* __restrict__ attnC, const float* __restrict__ pamT,
    const float* __restrict__ gpam, const float* __restrict__ gcam, float* __restrict__ out) {
  int b = blockIdx.z, c0 = blockIdx.y * 16, n0 = blockIdx.x * 256;
  int tid = threadIdx.x;
  __shared__ float pam_s[256 * 17];
#pragma unroll
  for (int k = 0; k < 16; k++) {
    int e = k * 256 + tid;
    int r = e >> 4, cc = e & 15;
    pam_s[r * 17 + cc] = pamT[((size_t)b * N_ + n0 + r) * C_ + c0 + cc];
  }
  __syncthreads();
  float acc[16];
#pragma unroll
  for (int i = 0; i < 16; i++) acc[i] = 0.f;
  const float* arow = attnC + ((size_t)b * C_ + c0) * C_;
  for (int j0 = 0; j0 < C_; j0 += 8) {
    float xv[8];
#pragma unroll
    for (int u = 0; u < 8; u++)          // 8 independent loads in flight
      xv[u] = x[((size_t)b * C_ + j0 + u) * N_ + n0 + tid];
#pragma unroll
    for (int i = 0; i < 16; i++)
#pragma unroll
      for (int u = 0; u < 8; u++)        // ascending j per acc[i] -> same order
        acc[i] += arow[i * C_ + j0 + u] * xv[u];
  }
  float gp = gpam[0], gc = gcam[0];
#pragma unroll
  for (int i = 0; i < 16; i++) {
    size_t idx = ((size_t)b * C_ + c0 + i) * N_ + n0 + tid;
    out[idx] = gp * pam_s[tid * 17 + i] + gc * acc[i] + 2.0f * x[idx];
  }
}

extern "C" void kernel_launch(void* const* d_in, const int* in_sizes, int n_in,
                              void* d_out, int out_size, void* d_ws, size_t ws_size,
                              hipStream_t stream) {
  const float* x  = (const float*)d_in[0];
  const float* wq = (const float*)d_in[1];
  const float* bq = (const float*)d_in[2];
  const float* wk = (const float*)d_in[3];
  const float* bk = (const float*)d_in[4];
  const float* wv = (const float*)d_in[5];
  const float* bv = (const float*)d_in[6];
  const float* gp = (const float*)d_in[7];
  const float* gc = (const float*)d_in[8];
  float* out = (float*)d_out;

  float* ws = (float*)d_ws;
  size_t o = 0;
  float* pamT  = ws + o; o += (size_t)B_ * N_ * C_;     // 2097152
  float* mp    = ws + o; o += (size_t)2 * B_ * N_;      // 16384 (j-half partial max)
  float* lp    = ws + o; o += (size_t)2 * B_ * N_;      // 16384 (j-half partial sum)
  float* eCp   = ws + o; o += (size_t)8 * B_ * C_ * C_; // 1048576
  float* attnC = ws + o; o += (size_t)B_ * C_ * C_;     // 131072
  bf16*  vbf   = (bf16*)(ws + o); o += (size_t)B_ * N_ * C_ / 2;   // 1048576
  bf16*  qhi   = (bf16*)(ws + o); o += (size_t)B_ * N_ * QK_ / 2;  // 131072
  bf16*  qlo   = (bf16*)(ws + o); o += (size_t)B_ * N_ * QK_ / 2;  // 131072
  bf16*  khi   = (bf16*)(ws + o); o += (size_t)B_ * N_ * QK_ / 2;  // 131072
  bf16*  klo   = (bf16*)(ws + o); o += (size_t)B_ * N_ * QK_ / 2;  // 131072
  float* qpprt = ws + o; o += (size_t)4 * B_ * N_ * QK_; // 1048576
  float* kpprt = ws + o; o += (size_t)4 * B_ * N_ * QK_; // 1048576
  // total ~6.8 M floats = 27.4 MB

  k_qk1<<<dim3(16, 4, B_), dim3(256), 0, stream>>>(x, wq, wk, qpprt, kpprt);
  k_qk2<<<dim3(32), dim3(256), 0, stream>>>(qpprt, kpprt, bq, bk, qhi, qlo, khi, klo);
  k_vbf<<<dim3(16, 32, B_), dim3(256), 0, stream>>>(x, wv, bv, vbf);
  k_pam2<<<dim3(N_ / 64, 2, B_), dim3(512), 0, stream>>>(qhi, qlo, khi, klo, mp, lp);
  k_pbm<<<dim3(N_ / 64, 2, B_), dim3(512), 0, stream>>>(qhi, qlo, khi, klo, vbf, mp, lp, pamT);
  k_ce<<<dim3(64, 8, B_), dim3(256), 0, stream>>>(x, eCp);
  k_cs<<<dim3(B_ * C_), dim3(256), 0, stream>>>(eCp, attnC);
  k_co<<<dim3(16, 16, B_), dim3(256), 0, stream>>>(x, attnC, pamT, gp, gc, out);
}

// Round 5
// 276.669 us; speedup vs baseline: 1.4459x; 1.1543x over previous
//
#include <hip/hip_runtime.h>
#include <hip/hip_bf16.h>

// DA block (DANet) — Round 22: MFMA CAM-out fused with final combine.
// R21 post-mortem: k_co (65 µs) is a latency-bound fp32 attnC×x matmul
// (VALUBusy 23%, 256 stride-N loads/thread). Replace with:
//   k_xt : x -> xT hi/lo bf16 [b][n][c] (aliased onto dead qpprt/kpprt)
//   k_cs : also emits attnC hi/lo bf16 (replaces fp32 attnC, same bytes)
//   k_cam: D[n][c] = sum_j xT[n][j]*attnC[c][j] via 3-MFMA hi/lo scheme,
//          epilogue fuses out = gp*pamT + gc*cam + 2x  (k_co removed).
// PAM path identical to R21-green -> pamT bit-identical.

#define B_ 2
#define C_ 256
#define N_ 4096
#define QK_ 32

#define TJ_ 128    // j per tile (8 waves x 16)
#define PPB_ 136   // p LDS pitch (bf16) = 272 B (16B-aligned rows)

typedef __hip_bfloat16 bf16;
typedef __attribute__((ext_vector_type(8))) short bf16x8f;   // MFMA A/B frag
typedef __attribute__((ext_vector_type(4))) float f32x4;     // MFMA C/D frag

union bf8pack { bf16 h[8]; int4 v; bf16x8f f; };

// ---- k_qk1: partial Q,K projections over a 64-channel chunk ----
__global__ __launch_bounds__(256) void k_qk1(
    const float* __restrict__ x, const float* __restrict__ wq, const float* __restrict__ wk,
    float* __restrict__ qp, float* __restrict__ kp) {
  int b = blockIdx.z;
  int cg = blockIdx.y;                      // 4 chunks of 64 channels
  int n = blockIdx.x * 256 + threadIdx.x;
  float qa[QK_], ka[QK_];
#pragma unroll
  for (int o = 0; o < QK_; o++) { qa[o] = 0.f; ka[o] = 0.f; }
  const float* xp = x + ((size_t)b * C_ + cg * 64) * N_ + n;
  for (int c = 0; c < 64; c++) {
    float xv = xp[(size_t)c * N_];
    int cc = cg * 64 + c;
#pragma unroll
    for (int o = 0; o < QK_; o++) {
      qa[o] += wq[o * C_ + cc] * xv;   // uniform weight loads -> scalar path
      ka[o] += wk[o * C_ + cc] * xv;
    }
  }
  float4* qo = (float4*)(qp + (((size_t)cg * B_ + b) * N_ + n) * QK_);
  float4* ko = (float4*)(kp + (((size_t)cg * B_ + b) * N_ + n) * QK_);
#pragma unroll
  for (int u = 0; u < 8; u++) {
    qo[u] = make_float4(qa[4 * u], qa[4 * u + 1], qa[4 * u + 2], qa[4 * u + 3]);
    ko[u] = make_float4(ka[4 * u], ka[4 * u + 1], ka[4 * u + 2], ka[4 * u + 3]);
  }
}

// ---- k_qk2 v2: combine partials + bias, emit hi/lo bf16 split arrays ----
__global__ __launch_bounds__(256) void k_qk2(
    const float* __restrict__ qp, const float* __restrict__ kp,
    const float* __restrict__ bq, const float* __restrict__ bk,
    bf16* __restrict__ qhi, bf16* __restrict__ qlo,
    bf16* __restrict__ khi, bf16* __restrict__ klo) {
  int t = blockIdx.x * 256 + threadIdx.x;    // b*N + n
  int b = t >> 12, n = t & (N_ - 1);
  float qa[QK_], ka[QK_];
#pragma unroll
  for (int o = 0; o < QK_; o++) { qa[o] = bq[o]; ka[o] = bk[o]; }
#pragma unroll
  for (int cg = 0; cg < 4; cg++) {
    const float4* qs = (const float4*)(qp + (((size_t)cg * B_ + b) * N_ + n) * QK_);
    const float4* ks = (const float4*)(kp + (((size_t)cg * B_ + b) * N_ + n) * QK_);
#pragma unroll
    for (int u = 0; u < 8; u++) {
      float4 q4 = qs[u], k4 = ks[u];
      qa[4 * u] += q4.x; qa[4 * u + 1] += q4.y; qa[4 * u + 2] += q4.z; qa[4 * u + 3] += q4.w;
      ka[4 * u] += k4.x; ka[4 * u + 1] += k4.y; ka[4 * u + 2] += k4.z; ka[4 * u + 3] += k4.w;
    }
  }
  size_t base = (size_t)t * QK_;
#pragma unroll
  for (int g = 0; g < 4; g++) {
    bf8pack qh, ql, kh, kl;
#pragma unroll
    for (int u = 0; u < 8; u++) {
      float qv = qa[g * 8 + u], kv = ka[g * 8 + u];
      bf16 qhh = __float2bfloat16(qv);
      bf16 khh = __float2bfloat16(kv);
      qh.h[u] = qhh; ql.h[u] = __float2bfloat16(qv - __bfloat162float(qhh));
      kh.h[u] = khh; kl.h[u] = __float2bfloat16(kv - __bfloat162float(khh));
    }
    *(int4*)(qhi + base + g * 8) = qh.v;
    *(int4*)(qlo + base + g * 8) = ql.v;
    *(int4*)(khi + base + g * 8) = kh.v;
    *(int4*)(klo + base + g * 8) = kl.v;
  }
}

// ---- k_xt: x[b][c][n] -> xT hi/lo bf16 [b][n][c] via 64x64 LDS tile ----
__global__ __launch_bounds__(256) void k_xt(
    const float* __restrict__ x, bf16* __restrict__ xthi, bf16* __restrict__ xtlo) {
  int b = blockIdx.z;
  int c0 = blockIdx.y * 64;
  int n0 = blockIdx.x * 64;
  __shared__ float t[64 * 65];
  int tid = threadIdx.x;
  int col = tid & 63, rowq = tid >> 6;        // 4 rows per pass
#pragma unroll
  for (int k = 0; k < 16; k++) {
    int r = k * 4 + rowq;
    t[r * 65 + col] = x[((size_t)b * C_ + c0 + r) * N_ + n0 + col];
  }
  __syncthreads();
#pragma unroll
  for (int k = 0; k < 16; k++) {
    int nrow = k * 4 + rowq;
    float v = t[col * 65 + nrow];             // [c_local=col][n_local=nrow]
    bf16 h = __float2bfloat16(v);
    size_t o = ((size_t)b * N_ + n0 + nrow) * C_ + c0 + col;
    xthi[o] = h;
    xtlo[o] = __float2bfloat16(v - __bfloat162float(h));
  }
}

// ---- k_vbf: V proj -> vbf[b,c,j] bf16; 8 channels/block ----
__global__ __launch_bounds__(256) void k_vbf(
    const float* __restrict__ x, const float* __restrict__ wv, const float* __restrict__ bv,
    bf16* __restrict__ vbf) {
  int b = blockIdx.z;
  int co0 = blockIdx.y * 8;
  int n0 = blockIdx.x * 256;
  int tid = threadIdx.x;
  float acc[8];
#pragma unroll
  for (int o = 0; o < 8; o++) acc[o] = bv[co0 + o];
  const float* xp = x + (size_t)b * C_ * N_ + n0 + tid;
  for (int c = 0; c < C_; c++) {
    float xv = xp[(size_t)c * N_];
#pragma unroll
    for (int o = 0; o < 8; o++) acc[o] += wv[(co0 + o) * C_ + c] * xv;
  }
#pragma unroll
  for (int o = 0; o < 8; o++)
    vbf[((size_t)b * C_ + co0 + o) * N_ + n0 + tid] = __float2bfloat16(acc[o]);
}

// ---- k_pam2 v5: TI=64, j-half split. Partial (m,l) per half ----
__global__ __launch_bounds__(512) void k_pam2(
    const bf16* __restrict__ qhi, const bf16* __restrict__ qlo,
    const bf16* __restrict__ khi, const bf16* __restrict__ klo,
    float* __restrict__ mp, float* __restrict__ lp) {
  int b = blockIdx.z;
  int jhalf = blockIdx.y;
  size_t j0 = (size_t)jhalf * (N_ / 2);
  int i0 = blockIdx.x * 64;
  int tid = threadIdx.x;
  int lane = tid & 63, wave = tid >> 6;
  int n16 = lane & 15, quad = lane >> 4;

  __shared__ float red_m[8 * 64], red_l[8 * 64];

  bf16x8f ahf[4], alf[4];
#pragma unroll
  for (int ih = 0; ih < 4; ih++) {
    size_t qoff = ((size_t)b * N_ + i0 + ih * 16 + n16) * QK_ + quad * 8;
    ahf[ih] = *(const bf16x8f*)(const void*)(qhi + qoff);
    alf[ih] = *(const bf16x8f*)(const void*)(qlo + qoff);
  }

  float m16[16], l16[16];
#pragma unroll
  for (int k = 0; k < 16; k++) { m16[k] = -3.0e38f; l16[k] = 0.f; }

  const bf16* khb = khi + ((size_t)b * N_ + j0 + wave * 16 + n16) * QK_ + quad * 8;
  const bf16* klb = klo + ((size_t)b * N_ + j0 + wave * 16 + n16) * QK_ + quad * 8;
  bf16x8f khf = *(const bf16x8f*)(const void*)khb;
  bf16x8f klf = *(const bf16x8f*)(const void*)klb;

  const int NJT = (N_ / 2) / TJ_;                // 16 iterations
  for (int jt = 0; jt < NJT; jt++) {
    bf16x8f khn, kln;
    if (jt + 1 < NJT) {
      size_t off = (size_t)(jt + 1) * TJ_ * QK_;
      khn = *(const bf16x8f*)(const void*)(khb + off);
      kln = *(const bf16x8f*)(const void*)(klb + off);
    }
#pragma unroll
    for (int ih = 0; ih < 4; ih++) {
      f32x4 z = (f32x4)(0.f);
      z = __builtin_amdgcn_mfma_f32_16x16x32_bf16(ahf[ih], khf, z, 0, 0, 0);
      z = __builtin_amdgcn_mfma_f32_16x16x32_bf16(alf[ih], khf, z, 0, 0, 0);
      z = __builtin_amdgcn_mfma_f32_16x16x32_bf16(ahf[ih], klf, z, 0, 0, 0);
#pragma unroll
      for (int r = 0; r < 4; r++) {
        int k = ih * 4 + r;
        float sv = z[r];
        float nm = fmaxf(m16[k], sv);
        l16[k] = l16[k] * __expf(m16[k] - nm) + __expf(sv - nm);
        m16[k] = nm;
      }
    }
    khf = khn; klf = kln;
  }
#pragma unroll
  for (int d = 1; d < 16; d <<= 1) {
#pragma unroll
    for (int k = 0; k < 16; k++) {
      float om = __shfl_xor(m16[k], d, 64);
      float ol = __shfl_xor(l16[k], d, 64);
      float nm = fmaxf(m16[k], om);
      l16[k] = l16[k] * __expf(m16[k] - nm) + ol * __expf(om - nm);
      m16[k] = nm;
    }
  }
  if (n16 == 0) {
#pragma unroll
    for (int ih = 0; ih < 4; ih++)
#pragma unroll
      for (int r = 0; r < 4; r++) {
        int i = ih * 16 + quad * 4 + r;
        red_m[wave * 64 + i] = m16[ih * 4 + r];
        red_l[wave * 64 + i] = l16[ih * 4 + r];
      }
  }
  __syncthreads();
  if (tid < 64) {
    float wm[8];
    float M = -3.0e38f;
#pragma unroll
    for (int w = 0; w < 8; w++) { wm[w] = red_m[w * 64 + tid]; M = fmaxf(M, wm[w]); }
    float L = 0.f;
#pragma unroll
    for (int w = 0; w < 8; w++) L += red_l[w * 64 + tid] * __expf(wm[w] - M);
    mp[((size_t)jhalf * B_ + b) * N_ + i0 + tid] = M;
    lp[((size_t)jhalf * B_ + b) * N_ + i0 + tid] = L;
  }
}

// ---- k_pbm v8: TI=64 rows x 128-ch half per block; grid (N/64, 2, B) ----
__global__ __launch_bounds__(512) void k_pbm(
    const bf16* __restrict__ qhi, const bf16* __restrict__ qlo,
    const bf16* __restrict__ khi, const bf16* __restrict__ klo,
    const bf16* __restrict__ vbf,
    const float* __restrict__ mp, const float* __restrict__ lp,
    float* __restrict__ pamT) {
  int b = blockIdx.z;
  int h0 = blockIdx.y * 128;                     // channel half
  int i0 = blockIdx.x * 64;
  int tid = threadIdx.x;
  int lane = tid & 63, wave = tid >> 6;
  int n16 = lane & 15, quad = lane >> 4;

  __shared__ __align__(16) bf16 p_s[2][64 * PPB_];   // 34.8 KB double-buffered

  float mreg[16], lireg[16];
#pragma unroll
  for (int ih = 0; ih < 4; ih++)
#pragma unroll
    for (int r = 0; r < 4; r++) {
      int i = i0 + ih * 16 + quad * 4 + r;
      float m0 = mp[(size_t)b * N_ + i],          l0 = lp[(size_t)b * N_ + i];
      float m1 = mp[((size_t)B_ + b) * N_ + i],   l1 = lp[((size_t)B_ + b) * N_ + i];
      float M = fmaxf(m0, m1);
      mreg[ih * 4 + r] = M;
      lireg[ih * 4 + r] = 1.0f / (l0 * __expf(m0 - M) + l1 * __expf(m1 - M));
    }

  bf16x8f ahf[4], alf[4];
#pragma unroll
  for (int ih = 0; ih < 4; ih++) {
    size_t qoff = ((size_t)b * N_ + i0 + ih * 16 + n16) * QK_ + quad * 8;
    ahf[ih] = *(const bf16x8f*)(const void*)(qhi + qoff);
    alf[ih] = *(const bf16x8f*)(const void*)(qlo + qoff);
  }

  f32x4 acc[4];
#pragma unroll
  for (int ih = 0; ih < 4; ih++) acc[ih] = (f32x4)(0.f);

  const bf16* khb = khi + ((size_t)b * N_ + wave * 16 + n16) * QK_ + quad * 8;
  const bf16* klb = klo + ((size_t)b * N_ + wave * 16 + n16) * QK_ + quad * 8;
  const bf16* vb0 = vbf + ((size_t)b * C_ + h0 + wave * 16 + n16) * N_ + quad * 8;

  bf16x8f khf = *(const bf16x8f*)(const void*)khb;
  bf16x8f klf = *(const bf16x8f*)(const void*)klb;
  bf16x8f vcur[4];
#pragma unroll
  for (int jh = 0; jh < 4; jh++)
    vcur[jh] = *(const bf16x8f*)(const void*)(vb0 + jh * 32);

  for (int jt = 0; jt < N_ / TJ_; jt++) {        // 32 iterations
    bf16x8f khn, kln, vnxt[4];
    if (jt + 1 < N_ / TJ_) {
      size_t koff = (size_t)(jt + 1) * TJ_ * QK_;
      khn = *(const bf16x8f*)(const void*)(khb + koff);
      kln = *(const bf16x8f*)(const void*)(klb + koff);
      int jb = (jt + 1) * TJ_;
#pragma unroll
      for (int jh = 0; jh < 4; jh++)
        vnxt[jh] = *(const bf16x8f*)(const void*)(vb0 + jb + jh * 32);
    }
    bf16* pbuf = p_s[jt & 1];
#pragma unroll
    for (int ih = 0; ih < 4; ih++) {
      f32x4 z = (f32x4)(0.f);
      z = __builtin_amdgcn_mfma_f32_16x16x32_bf16(ahf[ih], khf, z, 0, 0, 0);
      z = __builtin_amdgcn_mfma_f32_16x16x32_bf16(alf[ih], khf, z, 0, 0, 0);
      z = __builtin_amdgcn_mfma_f32_16x16x32_bf16(ahf[ih], klf, z, 0, 0, 0);
#pragma unroll
      for (int r = 0; r < 4; r++) {
        int i = ih * 16 + quad * 4 + r;
        float p = __expf(z[r] - mreg[ih * 4 + r]) * lireg[ih * 4 + r];
        pbuf[i * PPB_ + wave * 16 + n16] = __float2bfloat16(p);
      }
    }
    __syncthreads();   // the ONE barrier per iter (double-buffered p_s)
#pragma unroll
    for (int jh = 0; jh < 4; jh++) {
      bf16x8f pa[4];
#pragma unroll
      for (int ih = 0; ih < 4; ih++)
        pa[ih] = *(const bf16x8f*)(const void*)(pbuf + (ih * 16 + n16) * PPB_ + jh * 32 + quad * 8);
#pragma unroll
      for (int ih = 0; ih < 4; ih++)
        acc[ih] = __builtin_amdgcn_mfma_f32_16x16x32_bf16(pa[ih], vcur[jh], acc[ih], 0, 0, 0);
    }
    khf = khn; klf = kln;
#pragma unroll
    for (int jh = 0; jh < 4; jh++) vcur[jh] = vnxt[jh];
  }
  int c = h0 + wave * 16 + n16;
#pragma unroll
  for (int ih = 0; ih < 4; ih++)
#pragma unroll
    for (int r = 0; r < 4; r++) {
      int i = ih * 16 + quad * 4 + r;
      pamT[((size_t)b * N_ + i0 + i) * C_ + c] = acc[ih][r];
    }
}

// ---- k_ce: CAM energy partials over K-chunks ----
__global__ __launch_bounds__(256) void k_ce(const float* __restrict__ x, float* __restrict__ eCp) {
  int b = blockIdx.z;
  int kc = blockIdx.y;
  int it = blockIdx.x & 7, jt = blockIdx.x >> 3;
  int i0 = it * 32, j0 = jt * 32;
  __shared__ float xi[32 * 65], xj[32 * 65];
  int tid = threadIdx.x;
  int ti2 = (tid & 15) * 2, tj2 = (tid >> 4) * 2;
  float a00 = 0.f, a01 = 0.f, a10 = 0.f, a11 = 0.f;
  for (int n0 = 0; n0 < 512; n0 += 64) {
    __syncthreads();
#pragma unroll
    for (int k = 0; k < 8; k++) {
      int e = k * 256 + tid;
      int r = e >> 6, c = e & 63;
      xi[r * 65 + c] = x[((size_t)b * C_ + i0 + r) * N_ + kc * 512 + n0 + c];
      xj[r * 65 + c] = x[((size_t)b * C_ + j0 + r) * N_ + kc * 512 + n0 + c];
    }
    __syncthreads();
#pragma unroll 4
    for (int n = 0; n < 64; n++) {
      float u0 = xi[ti2 * 65 + n], u1 = xi[(ti2 + 1) * 65 + n];
      float w0 = xj[tj2 * 65 + n], w1 = xj[(tj2 + 1) * 65 + n];
      a00 += u0 * w0; a01 += u0 * w1; a10 += u1 * w0; a11 += u1 * w1;
    }
  }
  float* dst = eCp + (((size_t)kc * B_ + b) * C_ + i0) * C_ + j0;
  dst[(ti2 + 0) * C_ + tj2 + 0] = a00;
  dst[(ti2 + 0) * C_ + tj2 + 1] = a01;
  dst[(ti2 + 1) * C_ + tj2 + 0] = a10;
  dst[(ti2 + 1) * C_ + tj2 + 1] = a11;
}

// ---- k_cs v2: CAM softmax over -e; emit bf16 hi/lo ----
__global__ __launch_bounds__(256) void k_cs(
    const float* __restrict__ eCp, bf16* __restrict__ ahi, bf16* __restrict__ alo) {
  int row = blockIdx.x;
  int b = row >> 8, i = row & 255;
  int j = threadIdx.x;
  float e = 0.f;
#pragma unroll
  for (int kc = 0; kc < 8; kc++) e += eCp[(((size_t)kc * B_ + b) * C_ + i) * C_ + j];
  float ne = -e;
  __shared__ float buf[256];
  buf[j] = ne;
  __syncthreads();
  for (int st = 128; st >= 1; st >>= 1) {
    if (j < st) buf[j] = fmaxf(buf[j], buf[j + st]);
    __syncthreads();
  }
  float m = buf[0];
  __syncthreads();
  float p = __expf(ne - m);
  buf[j] = p;
  __syncthreads();
  for (int st = 128; st >= 1; st >>= 1) {
    if (j < st) buf[j] += buf[j + st];
    __syncthreads();
  }
  float v = p / buf[0];
  bf16 h = __float2bfloat16(v);
  ahi[(size_t)row * C_ + j] = h;
  alo[(size_t)row * C_ + j] = __float2bfloat16(v - __bfloat162float(h));
}

// ---- k_cam: cam[n][c] = sum_j xT[n][j]*attnC[c][j] (3-MFMA hi/lo),
//      fused: out = gp*pamT + gc*cam + 2x. grid (N/32, B), 512 thr ----
__global__ __launch_bounds__(512) void k_cam(
    const bf16* __restrict__ xthi, const bf16* __restrict__ xtlo,
    const bf16* __restrict__ ahi, const bf16* __restrict__ alo,
    const float* __restrict__ pamT, const float* __restrict__ x,
    const float* __restrict__ gpam, const float* __restrict__ gcam,
    float* __restrict__ out) {
  int b = blockIdx.y;
  int n0 = blockIdx.x * 32;
  int tid = threadIdx.x;
  int lane = tid & 63, wave = tid >> 6;
  int n16 = lane & 15, quad = lane >> 4;
  int c0 = wave * 32;

  f32x4 acc[2][2];                               // [nt][ct]
#pragma unroll
  for (int nt = 0; nt < 2; nt++)
#pragma unroll
    for (int ct = 0; ct < 2; ct++) acc[nt][ct] = (f32x4)(0.f);

#pragma unroll
  for (int kk = 0; kk < 8; kk++) {               // K = 256 = 8 x 32
    bf16x8f Ah[2], Al[2], Bh[2], Bl[2];
#pragma unroll
    for (int nt = 0; nt < 2; nt++) {
      size_t off = ((size_t)b * N_ + n0 + nt * 16 + n16) * C_ + kk * 32 + quad * 8;
      Ah[nt] = *(const bf16x8f*)(const void*)(xthi + off);
      Al[nt] = *(const bf16x8f*)(const void*)(xtlo + off);
    }
#pragma unroll
    for (int ct = 0; ct < 2; ct++) {
      size_t off = ((size_t)b * C_ + c0 + ct * 16 + n16) * C_ + kk * 32 + quad * 8;
      Bh[ct] = *(const bf16x8f*)(const void*)(ahi + off);
      Bl[ct] = *(const bf16x8f*)(const void*)(alo + off);
    }
#pragma unroll
    for (int nt = 0; nt < 2; nt++)
#pragma unroll
      for (int ct = 0; ct < 2; ct++) {
        acc[nt][ct] = __builtin_amdgcn_mfma_f32_16x16x32_bf16(Ah[nt], Bh[ct], acc[nt][ct], 0, 0, 0);
        acc[nt][ct] = __builtin_amdgcn_mfma_f32_16x16x32_bf16(Al[nt], Bh[ct], acc[nt][ct], 0, 0, 0);
        acc[nt][ct] = __builtin_amdgcn_mfma_f32_16x16x32_bf16(Ah[nt], Bl[ct], acc[nt][ct], 0, 0, 0);
      }
  }
  float gp = gpam[0], gc = gcam[0];
#pragma unroll
  for (int nt = 0; nt < 2; nt++)
#pragma unroll
    for (int ct = 0; ct < 2; ct++) {
      int c = c0 + ct * 16 + n16;
      int nb = n0 + nt * 16 + quad * 4;
      const float* xp = x + ((size_t)b * C_ + c) * N_ + nb;
      float4 x4 = *(const float4*)(const void*)xp;
      float4 o4;
      o4.x = gp * pamT[((size_t)b * N_ + nb + 0) * C_ + c] + gc * acc[nt][ct][0] + 2.0f * x4.x;
      o4.y = gp * pamT[((size_t)b * N_ + nb + 1) * C_ + c] + gc * acc[nt][ct][1] + 2.0f * x4.y;
      o4.z = gp * pamT[((size_t)b * N_ + nb + 2) * C_ + c] + gc * acc[nt][ct][2] + 2.0f * x4.z;
      o4.w = gp * pamT[((size_t)b * N_ + nb + 3) * C_ + c] + gc * acc[nt][ct][3] + 2.0f * x4.w;
      *(float4*)(out + ((size_t)b * C_ + c) * N_ + nb) = o4;
    }
}

extern "C" void kernel_launch(void* const* d_in, const int* in_sizes, int n_in,
                              void* d_out, int out_size, void* d_ws, size_t ws_size,
                              hipStream_t stream) {
  const float* x  = (const float*)d_in[0];
  const float* wq = (const float*)d_in[1];
  const float* bq = (const float*)d_in[2];
  const float* wk = (const float*)d_in[3];
  const float* bk = (const float*)d_in[4];
  const float* wv = (const float*)d_in[5];
  const float* bv = (const float*)d_in[6];
  const float* gp = (const float*)d_in[7];
  const float* gc = (const float*)d_in[8];
  float* out = (float*)d_out;

  float* ws = (float*)d_ws;
  size_t o = 0;
  float* pamT  = ws + o; o += (size_t)B_ * N_ * C_;     // 2097152
  float* mp    = ws + o; o += (size_t)2 * B_ * N_;      // 16384
  float* lp    = ws + o; o += (size_t)2 * B_ * N_;      // 16384
  float* eCp   = ws + o; o += (size_t)8 * B_ * C_ * C_; // 1048576
  bf16*  ahi   = (bf16*)(ws + o); o += (size_t)B_ * C_ * C_ / 2;   // 65536 fl
  bf16*  alo   = (bf16*)(ws + o); o += (size_t)B_ * C_ * C_ / 2;   // 65536 fl
  bf16*  vbf   = (bf16*)(ws + o); o += (size_t)B_ * N_ * C_ / 2;   // 1048576
  bf16*  qhi   = (bf16*)(ws + o); o += (size_t)B_ * N_ * QK_ / 2;  // 131072
  bf16*  qlo   = (bf16*)(ws + o); o += (size_t)B_ * N_ * QK_ / 2;  // 131072
  bf16*  khi   = (bf16*)(ws + o); o += (size_t)B_ * N_ * QK_ / 2;  // 131072
  bf16*  klo   = (bf16*)(ws + o); o += (size_t)B_ * N_ * QK_ / 2;  // 131072
  float* qpprt = ws + o; o += (size_t)4 * B_ * N_ * QK_; // 1048576
  float* kpprt = ws + o; o += (size_t)4 * B_ * N_ * QK_; // 1048576
  // xT hi/lo alias the dead q/k partial buffers (exact fit: 2M bf16 = 4 MB)
  bf16* xthi = (bf16*)qpprt;
  bf16* xtlo = (bf16*)kpprt;
  // total ~6.8 M floats = 27.4 MB (unchanged)

  k_qk1<<<dim3(16, 4, B_), dim3(256), 0, stream>>>(x, wq, wk, qpprt, kpprt);
  k_qk2<<<dim3(32), dim3(256), 0, stream>>>(qpprt, kpprt, bq, bk, qhi, qlo, khi, klo);
  k_xt<<<dim3(N_ / 64, C_ / 64, B_), dim3(256), 0, stream>>>(x, xthi, xtlo);
  k_vbf<<<dim3(16, 32, B_), dim3(256), 0, stream>>>(x, wv, bv, vbf);
  k_pam2<<<dim3(N_ / 64, 2, B_), dim3(512), 0, stream>>>(qhi, qlo, khi, klo, mp, lp);
  k_pbm<<<dim3(N_ / 64, 2, B_), dim3(512), 0, stream>>>(qhi, qlo, khi, klo, vbf, mp, lp, pamT);
  k_ce<<<dim3(64, 8, B_), dim3(256), 0, stream>>>(x, eCp);
  k_cs<<<dim3(B_ * C_), dim3(256), 0, stream>>>(eCp, ahi, alo);
  k_cam<<<dim3(N_ / 32, B_), dim3(512), 0, stream>>>(xthi, xtlo, ahi, alo, pamT, x, gp, gc, out);
}

// Round 6
// 231.983 us; speedup vs baseline: 1.7244x; 1.1926x over previous
//
#include <hip/hip_runtime.h>
#include <hip/hip_bf16.h>

// DA block (DANet) — Round 23: MFMA-ize the projection matmuls.
// R22 counters: k_pbm 58 µs (top-1, deferred); remaining ~210 µs spread over
// scalar fp32 matmuls. Replace k_qk1+k_qk2+k_vbf with k_cam-pattern hi/lo
// bf16 MFMA kernels consuming xT (already built by k_xt):
//   k_wcv : one-time wq/wk/wv -> hi/lo bf16 (aliased onto eCp, dead til k_ce)
//   k_qkp : q/k proj, A=wqk[64x256] B=xT, packed 8B hi/lo stores
//   k_vbf2: V proj,  A=wv  [256x256] B=xT -> vbf bf16
// PAM/CAM kernels (k_xt,k_pam2,k_pbm,k_ce,k_cs,k_cam) identical to R22-green.

#define B_ 2
#define C_ 256
#define N_ 4096
#define QK_ 32

#define TJ_ 128    // j per tile (8 waves x 16)
#define PPB_ 136   // p LDS pitch (bf16) = 272 B (16B-aligned rows)

typedef __hip_bfloat16 bf16;
typedef __attribute__((ext_vector_type(8))) short bf16x8f;   // MFMA A/B frag
typedef __attribute__((ext_vector_type(4))) float f32x4;     // MFMA C/D frag

union bf8pack { bf16 h[8]; int4 v; bf16x8f f; };
union bf4pack { bf16 h[4]; uint2 u; };

// ---- k_wcv: weights -> hi/lo bf16. wqk = [wq;wk] 64x256, wv 256x256 ----
__global__ __launch_bounds__(256) void k_wcv(
    const float* __restrict__ wq, const float* __restrict__ wk, const float* __restrict__ wv,
    bf16* __restrict__ wqkh, bf16* __restrict__ wqkl,
    bf16* __restrict__ wvh, bf16* __restrict__ wvl) {
  int idx = blockIdx.x * 256 + threadIdx.x;
  if (idx < 64 * C_) {
    int r = idx >> 8, c = idx & 255;
    float v = (r < 32) ? wq[r * C_ + c] : wk[(r - 32) * C_ + c];
    bf16 h = __float2bfloat16(v);
    wqkh[idx] = h; wqkl[idx] = __float2bfloat16(v - __bfloat162float(h));
  } else {
    int j = idx - 64 * C_;
    float v = wv[j];
    bf16 h = __float2bfloat16(v);
    wvh[j] = h; wvl[j] = __float2bfloat16(v - __bfloat162float(h));
  }
}

// ---- k_xt: x[b][c][n] -> xT hi/lo bf16 [b][n][c] via 64x64 LDS tile ----
__global__ __launch_bounds__(256) void k_xt(
    const float* __restrict__ x, bf16* __restrict__ xthi, bf16* __restrict__ xtlo) {
  int b = blockIdx.z;
  int c0 = blockIdx.y * 64;
  int n0 = blockIdx.x * 64;
  __shared__ float t[64 * 65];
  int tid = threadIdx.x;
  int col = tid & 63, rowq = tid >> 6;        // 4 rows per pass
#pragma unroll
  for (int k = 0; k < 16; k++) {
    int r = k * 4 + rowq;
    t[r * 65 + col] = x[((size_t)b * C_ + c0 + r) * N_ + n0 + col];
  }
  __syncthreads();
#pragma unroll
  for (int k = 0; k < 16; k++) {
    int nrow = k * 4 + rowq;
    float v = t[col * 65 + nrow];             // [c_local=col][n_local=nrow]
    bf16 h = __float2bfloat16(v);
    size_t o = ((size_t)b * N_ + n0 + nrow) * C_ + c0 + col;
    xthi[o] = h;
    xtlo[o] = __float2bfloat16(v - __bfloat162float(h));
  }
}

// ---- k_qkp: q/k proj via MFMA. A=wqk (rows o), B=xT (rows n), K=256 ----
// Wave: 64 o x 32 n. Block 4 waves = 128 n. Packed 8B hi/lo stores.
__global__ __launch_bounds__(256) void k_qkp(
    const bf16* __restrict__ xthi, const bf16* __restrict__ xtlo,
    const bf16* __restrict__ wqkh, const bf16* __restrict__ wqkl,
    const float* __restrict__ bq, const float* __restrict__ bk,
    bf16* __restrict__ qhi, bf16* __restrict__ qlo,
    bf16* __restrict__ khi, bf16* __restrict__ klo) {
  int b = blockIdx.y;
  int tid = threadIdx.x;
  int lane = tid & 63, wave = tid >> 6;
  int n16 = lane & 15, quad = lane >> 4;
  int nb = blockIdx.x * 128 + wave * 32;

  f32x4 acc[4][2];                              // [ot][nt]
#pragma unroll
  for (int ot = 0; ot < 4; ot++)
#pragma unroll
    for (int nt = 0; nt < 2; nt++) acc[ot][nt] = (f32x4)(0.f);

#pragma unroll
  for (int kk = 0; kk < 8; kk++) {
    bf16x8f Ah[4], Al[4], Bh[2], Bl[2];
#pragma unroll
    for (int ot = 0; ot < 4; ot++) {
      size_t off = (size_t)(ot * 16 + n16) * C_ + kk * 32 + quad * 8;
      Ah[ot] = *(const bf16x8f*)(const void*)(wqkh + off);
      Al[ot] = *(const bf16x8f*)(const void*)(wqkl + off);
    }
#pragma unroll
    for (int nt = 0; nt < 2; nt++) {
      size_t off = ((size_t)b * N_ + nb + nt * 16 + n16) * C_ + kk * 32 + quad * 8;
      Bh[nt] = *(const bf16x8f*)(const void*)(xthi + off);
      Bl[nt] = *(const bf16x8f*)(const void*)(xtlo + off);
    }
#pragma unroll
    for (int ot = 0; ot < 4; ot++)
#pragma unroll
      for (int nt = 0; nt < 2; nt++) {
        acc[ot][nt] = __builtin_amdgcn_mfma_f32_16x16x32_bf16(Ah[ot], Bh[nt], acc[ot][nt], 0, 0, 0);
        acc[ot][nt] = __builtin_amdgcn_mfma_f32_16x16x32_bf16(Al[ot], Bh[nt], acc[ot][nt], 0, 0, 0);
        acc[ot][nt] = __builtin_amdgcn_mfma_f32_16x16x32_bf16(Ah[ot], Bl[nt], acc[ot][nt], 0, 0, 0);
      }
  }
#pragma unroll
  for (int ot = 0; ot < 4; ot++)
#pragma unroll
    for (int nt = 0; nt < 2; nt++) {
      int n = nb + nt * 16 + n16;
      int o0 = (ot & 1) * 16 + quad * 4;        // o within q or k (0..31)
      bf4pack ph, pl;
#pragma unroll
      for (int r = 0; r < 4; r++) {
        float v = acc[ot][nt][r] + (ot < 2 ? bq[o0 + r] : bk[o0 + r]);
        bf16 h = __float2bfloat16(v);
        ph.h[r] = h; pl.h[r] = __float2bfloat16(v - __bfloat162float(h));
      }
      size_t base = ((size_t)b * N_ + n) * QK_ + o0;
      if (ot < 2) { *(uint2*)(qhi + base) = ph.u; *(uint2*)(qlo + base) = pl.u; }
      else        { *(uint2*)(khi + base) = ph.u; *(uint2*)(klo + base) = pl.u; }
    }
}

// ---- k_vbf2: V proj via MFMA. A=wv (rows c), B=xT (rows n), K=256 ----
// Wave: 64 c x 32 n. Block 4 waves = 256 c. Grid (N/32, B) = 256 blocks.
__global__ __launch_bounds__(256) void k_vbf2(
    const bf16* __restrict__ xthi, const bf16* __restrict__ xtlo,
    const bf16* __restrict__ wvh, const bf16* __restrict__ wvl,
    const float* __restrict__ bv, bf16* __restrict__ vbf) {
  int b = blockIdx.y;
  int n0 = blockIdx.x * 32;
  int tid = threadIdx.x;
  int lane = tid & 63, wave = tid >> 6;
  int n16 = lane & 15, quad = lane >> 4;
  int c0 = wave * 64;

  f32x4 acc[4][2];                              // [ct][nt]
#pragma unroll
  for (int ct = 0; ct < 4; ct++)
#pragma unroll
    for (int nt = 0; nt < 2; nt++) acc[ct][nt] = (f32x4)(0.f);

#pragma unroll
  for (int kk = 0; kk < 8; kk++) {
    bf16x8f Ah[4], Al[4], Bh[2], Bl[2];
#pragma unroll
    for (int ct = 0; ct < 4; ct++) {
      size_t off = (size_t)(c0 + ct * 16 + n16) * C_ + kk * 32 + quad * 8;
      Ah[ct] = *(const bf16x8f*)(const void*)(wvh + off);
      Al[ct] = *(const bf16x8f*)(const void*)(wvl + off);
    }
#pragma unroll
    for (int nt = 0; nt < 2; nt++) {
      size_t off = ((size_t)b * N_ + n0 + nt * 16 + n16) * C_ + kk * 32 + quad * 8;
      Bh[nt] = *(const bf16x8f*)(const void*)(xthi + off);
      Bl[nt] = *(const bf16x8f*)(const void*)(xtlo + off);
    }
#pragma unroll
    for (int ct = 0; ct < 4; ct++)
#pragma unroll
      for (int nt = 0; nt < 2; nt++) {
        acc[ct][nt] = __builtin_amdgcn_mfma_f32_16x16x32_bf16(Ah[ct], Bh[nt], acc[ct][nt], 0, 0, 0);
        acc[ct][nt] = __builtin_amdgcn_mfma_f32_16x16x32_bf16(Al[ct], Bh[nt], acc[ct][nt], 0, 0, 0);
        acc[ct][nt] = __builtin_amdgcn_mfma_f32_16x16x32_bf16(Ah[ct], Bl[nt], acc[ct][nt], 0, 0, 0);
      }
  }
#pragma unroll
  for (int ct = 0; ct < 4; ct++)
#pragma unroll
    for (int nt = 0; nt < 2; nt++) {
      int n = n0 + nt * 16 + n16;
      int cb = c0 + ct * 16 + quad * 4;
#pragma unroll
      for (int r = 0; r < 4; r++) {
        float v = acc[ct][nt][r] + bv[cb + r];
        vbf[((size_t)b * C_ + cb + r) * N_ + n] = __float2bfloat16(v);
      }
    }
}

// ---- k_pam2 v5: TI=64, j-half split. Partial (m,l) per half ----
__global__ __launch_bounds__(512) void k_pam2(
    const bf16* __restrict__ qhi, const bf16* __restrict__ qlo,
    const bf16* __restrict__ khi, const bf16* __restrict__ klo,
    float* __restrict__ mp, float* __restrict__ lp) {
  int b = blockIdx.z;
  int jhalf = blockIdx.y;
  size_t j0 = (size_t)jhalf * (N_ / 2);
  int i0 = blockIdx.x * 64;
  int tid = threadIdx.x;
  int lane = tid & 63, wave = tid >> 6;
  int n16 = lane & 15, quad = lane >> 4;

  __shared__ float red_m[8 * 64], red_l[8 * 64];

  bf16x8f ahf[4], alf[4];
#pragma unroll
  for (int ih = 0; ih < 4; ih++) {
    size_t qoff = ((size_t)b * N_ + i0 + ih * 16 + n16) * QK_ + quad * 8;
    ahf[ih] = *(const bf16x8f*)(const void*)(qhi + qoff);
    alf[ih] = *(const bf16x8f*)(const void*)(qlo + qoff);
  }

  float m16[16], l16[16];
#pragma unroll
  for (int k = 0; k < 16; k++) { m16[k] = -3.0e38f; l16[k] = 0.f; }

  const bf16* khb = khi + ((size_t)b * N_ + j0 + wave * 16 + n16) * QK_ + quad * 8;
  const bf16* klb = klo + ((size_t)b * N_ + j0 + wave * 16 + n16) * QK_ + quad * 8;
  bf16x8f khf = *(const bf16x8f*)(const void*)khb;
  bf16x8f klf = *(const bf16x8f*)(const void*)klb;

  const int NJT = (N_ / 2) / TJ_;                // 16 iterations
  for (int jt = 0; jt < NJT; jt++) {
    bf16x8f khn, kln;
    if (jt + 1 < NJT) {
      size_t off = (size_t)(jt + 1) * TJ_ * QK_;
      khn = *(const bf16x8f*)(const void*)(khb + off);
      kln = *(const bf16x8f*)(const void*)(klb + off);
    }
#pragma unroll
    for (int ih = 0; ih < 4; ih++) {
      f32x4 z = (f32x4)(0.f);
      z = __builtin_amdgcn_mfma_f32_16x16x32_bf16(ahf[ih], khf, z, 0, 0, 0);
      z = __builtin_amdgcn_mfma_f32_16x16x32_bf16(alf[ih], khf, z, 0, 0, 0);
      z = __builtin_amdgcn_mfma_f32_16x16x32_bf16(ahf[ih], klf, z, 0, 0, 0);
#pragma unroll
      for (int r = 0; r < 4; r++) {
        int k = ih * 4 + r;
        float sv = z[r];
        float nm = fmaxf(m16[k], sv);
        l16[k] = l16[k] * __expf(m16[k] - nm) + __expf(sv - nm);
        m16[k] = nm;
      }
    }
    khf = khn; klf = kln;
  }
#pragma unroll
  for (int d = 1; d < 16; d <<= 1) {
#pragma unroll
    for (int k = 0; k < 16; k++) {
      float om = __shfl_xor(m16[k], d, 64);
      float ol = __shfl_xor(l16[k], d, 64);
      float nm = fmaxf(m16[k], om);
      l16[k] = l16[k] * __expf(m16[k] - nm) + ol * __expf(om - nm);
      m16[k] = nm;
    }
  }
  if (n16 == 0) {
#pragma unroll
    for (int ih = 0; ih < 4; ih++)
#pragma unroll
      for (int r = 0; r < 4; r++) {
        int i = ih * 16 + quad * 4 + r;
        red_m[wave * 64 + i] = m16[ih * 4 + r];
        red_l[wave * 64 + i] = l16[ih * 4 + r];
      }
  }
  __syncthreads();
  if (tid < 64) {
    float wm[8];
    float M = -3.0e38f;
#pragma unroll
    for (int w = 0; w < 8; w++) { wm[w] = red_m[w * 64 + tid]; M = fmaxf(M, wm[w]); }
    float L = 0.f;
#pragma unroll
    for (int w = 0; w < 8; w++) L += red_l[w * 64 + tid] * __expf(wm[w] - M);
    mp[((size_t)jhalf * B_ + b) * N_ + i0 + tid] = M;
    lp[((size_t)jhalf * B_ + b) * N_ + i0 + tid] = L;
  }
}

// ---- k_pbm v8: TI=64 rows x 128-ch half per block; grid (N/64, 2, B) ----
__global__ __launch_bounds__(512) void k_pbm(
    const bf16* __restrict__ qhi, const bf16* __restrict__ qlo,
    const bf16* __restrict__ khi, const bf16* __restrict__ klo,
    const bf16* __restrict__ vbf,
    const float* __restrict__ mp, const float* __restrict__ lp,
    float* __restrict__ pamT) {
  int b = blockIdx.z;
  int h0 = blockIdx.y * 128;                     // channel half
  int i0 = blockIdx.x * 64;
  int tid = threadIdx.x;
  int lane = tid & 63, wave = tid >> 6;
  int n16 = lane & 15, quad = lane >> 4;

  __shared__ __align__(16) bf16 p_s[2][64 * PPB_];   // 34.8 KB double-buffered

  float mreg[16], lireg[16];
#pragma unroll
  for (int ih = 0; ih < 4; ih++)
#pragma unroll
    for (int r = 0; r < 4; r++) {
      int i = i0 + ih * 16 + quad * 4 + r;
      float m0 = mp[(size_t)b * N_ + i],          l0 = lp[(size_t)b * N_ + i];
      float m1 = mp[((size_t)B_ + b) * N_ + i],   l1 = lp[((size_t)B_ + b) * N_ + i];
      float M = fmaxf(m0, m1);
      mreg[ih * 4 + r] = M;
      lireg[ih * 4 + r] = 1.0f / (l0 * __expf(m0 - M) + l1 * __expf(m1 - M));
    }

  bf16x8f ahf[4], alf[4];
#pragma unroll
  for (int ih = 0; ih < 4; ih++) {
    size_t qoff = ((size_t)b * N_ + i0 + ih * 16 + n16) * QK_ + quad * 8;
    ahf[ih] = *(const bf16x8f*)(const void*)(qhi + qoff);
    alf[ih] = *(const bf16x8f*)(const void*)(qlo + qoff);
  }

  f32x4 acc[4];
#pragma unroll
  for (int ih = 0; ih < 4; ih++) acc[ih] = (f32x4)(0.f);

  const bf16* khb = khi + ((size_t)b * N_ + wave * 16 + n16) * QK_ + quad * 8;
  const bf16* klb = klo + ((size_t)b * N_ + wave * 16 + n16) * QK_ + quad * 8;
  const bf16* vb0 = vbf + ((size_t)b * C_ + h0 + wave * 16 + n16) * N_ + quad * 8;

  bf16x8f khf = *(const bf16x8f*)(const void*)khb;
  bf16x8f klf = *(const bf16x8f*)(const void*)klb;
  bf16x8f vcur[4];
#pragma unroll
  for (int jh = 0; jh < 4; jh++)
    vcur[jh] = *(const bf16x8f*)(const void*)(vb0 + jh * 32);

  for (int jt = 0; jt < N_ / TJ_; jt++) {        // 32 iterations
    bf16x8f khn, kln, vnxt[4];
    if (jt + 1 < N_ / TJ_) {
      size_t koff = (size_t)(jt + 1) * TJ_ * QK_;
      khn = *(const bf16x8f*)(const void*)(khb + koff);
      kln = *(const bf16x8f*)(const void*)(klb + koff);
      int jb = (jt + 1) * TJ_;
#pragma unroll
      for (int jh = 0; jh < 4; jh++)
        vnxt[jh] = *(const bf16x8f*)(const void*)(vb0 + jb + jh * 32);
    }
    bf16* pbuf = p_s[jt & 1];
#pragma unroll
    for (int ih = 0; ih < 4; ih++) {
      f32x4 z = (f32x4)(0.f);
      z = __builtin_amdgcn_mfma_f32_16x16x32_bf16(ahf[ih], khf, z, 0, 0, 0);
      z = __builtin_amdgcn_mfma_f32_16x16x32_bf16(alf[ih], khf, z, 0, 0, 0);
      z = __builtin_amdgcn_mfma_f32_16x16x32_bf16(ahf[ih], klf, z, 0, 0, 0);
#pragma unroll
      for (int r = 0; r < 4; r++) {
        int i = ih * 16 + quad * 4 + r;
        float p = __expf(z[r] - mreg[ih * 4 + r]) * lireg[ih * 4 + r];
        pbuf[i * PPB_ + wave * 16 + n16] = __float2bfloat16(p);
      }
    }
    __syncthreads();   // the ONE barrier per iter (double-buffered p_s)
#pragma unroll
    for (int jh = 0; jh < 4; jh++) {
      bf16x8f pa[4];
#pragma unroll
      for (int ih = 0; ih < 4; ih++)
        pa[ih] = *(const bf16x8f*)(const void*)(pbuf + (ih * 16 + n16) * PPB_ + jh * 32 + quad * 8);
#pragma unroll
      for (int ih = 0; ih < 4; ih++)
        acc[ih] = __builtin_amdgcn_mfma_f32_16x16x32_bf16(pa[ih], vcur[jh], acc[ih], 0, 0, 0);
    }
    khf = khn; klf = kln;
#pragma unroll
    for (int jh = 0; jh < 4; jh++) vcur[jh] = vnxt[jh];
  }
  int c = h0 + wave * 16 + n16;
#pragma unroll
  for (int ih = 0; ih < 4; ih++)
#pragma unroll
    for (int r = 0; r < 4; r++) {
      int i = ih * 16 + quad * 4 + r;
      pamT[((size_t)b * N_ + i0 + i) * C_ + c] = acc[ih][r];
    }
}

// ---- k_ce: CAM energy partials over K-chunks ----
__global__ __launch_bounds__(256) void k_ce(const float* __restrict__ x, float* __restrict__ eCp) {
  int b = blockIdx.z;
  int kc = blockIdx.y;
  int it = blockIdx.x & 7, jt = blockIdx.x >> 3;
  int i0 = it * 32, j0 = jt * 32;
  __shared__ float xi[32 * 65], xj[32 * 65];
  int tid = threadIdx.x;
  int ti2 = (tid & 15) * 2, tj2 = (tid >> 4) * 2;
  float a00 = 0.f, a01 = 0.f, a10 = 0.f, a11 = 0.f;
  for (int n0 = 0; n0 < 512; n0 += 64) {
    __syncthreads();
#pragma unroll
    for (int k = 0; k < 8; k++) {
      int e = k * 256 + tid;
      int r = e >> 6, c = e & 63;
      xi[r * 65 + c] = x[((size_t)b * C_ + i0 + r) * N_ + kc * 512 + n0 + c];
      xj[r * 65 + c] = x[((size_t)b * C_ + j0 + r) * N_ + kc * 512 + n0 + c];
    }
    __syncthreads();
#pragma unroll 4
    for (int n = 0; n < 64; n++) {
      float u0 = xi[ti2 * 65 + n], u1 = xi[(ti2 + 1) * 65 + n];
      float w0 = xj[tj2 * 65 + n], w1 = xj[(tj2 + 1) * 65 + n];
      a00 += u0 * w0; a01 += u0 * w1; a10 += u1 * w0; a11 += u1 * w1;
    }
  }
  float* dst = eCp + (((size_t)kc * B_ + b) * C_ + i0) * C_ + j0;
  dst[(ti2 + 0) * C_ + tj2 + 0] = a00;
  dst[(ti2 + 0) * C_ + tj2 + 1] = a01;
  dst[(ti2 + 1) * C_ + tj2 + 0] = a10;
  dst[(ti2 + 1) * C_ + tj2 + 1] = a11;
}

// ---- k_cs v2: CAM softmax over -e; emit bf16 hi/lo ----
__global__ __launch_bounds__(256) void k_cs(
    const float* __restrict__ eCp, bf16* __restrict__ ahi, bf16* __restrict__ alo) {
  int row = blockIdx.x;
  int b = row >> 8, i = row & 255;
  int j = threadIdx.x;
  float e = 0.f;
#pragma unroll
  for (int kc = 0; kc < 8; kc++) e += eCp[(((size_t)kc * B_ + b) * C_ + i) * C_ + j];
  float ne = -e;
  __shared__ float buf[256];
  buf[j] = ne;
  __syncthreads();
  for (int st = 128; st >= 1; st >>= 1) {
    if (j < st) buf[j] = fmaxf(buf[j], buf[j + st]);
    __syncthreads();
  }
  float m = buf[0];
  __syncthreads();
  float p = __expf(ne - m);
  buf[j] = p;
  __syncthreads();
  for (int st = 128; st >= 1; st >>= 1) {
    if (j < st) buf[j] += buf[j + st];
    __syncthreads();
  }
  float v = p / buf[0];
  bf16 h = __float2bfloat16(v);
  ahi[(size_t)row * C_ + j] = h;
  alo[(size_t)row * C_ + j] = __float2bfloat16(v - __bfloat162float(h));
}

// ---- k_cam: cam[n][c] = sum_j xT[n][j]*attnC[c][j] (3-MFMA hi/lo),
//      fused: out = gp*pamT + gc*cam + 2x. grid (N/32, B), 512 thr ----
__global__ __launch_bounds__(512) void k_cam(
    const bf16* __restrict__ xthi, const bf16* __restrict__ xtlo,
    const bf16* __restrict__ ahi, const bf16* __restrict__ alo,
    const float* __restrict__ pamT, const float* __restrict__ x,
    const float* __restrict__ gpam, const float* __restrict__ gcam,
    float* __restrict__ out) {
  int b = blockIdx.y;
  int n0 = blockIdx.x * 32;
  int tid = threadIdx.x;
  int lane = tid & 63, wave = tid >> 6;
  int n16 = lane & 15, quad = lane >> 4;
  int c0 = wave * 32;

  f32x4 acc[2][2];                               // [nt][ct]
#pragma unroll
  for (int nt = 0; nt < 2; nt++)
#pragma unroll
    for (int ct = 0; ct < 2; ct++) acc[nt][ct] = (f32x4)(0.f);

#pragma unroll
  for (int kk = 0; kk < 8; kk++) {               // K = 256 = 8 x 32
    bf16x8f Ah[2], Al[2], Bh[2], Bl[2];
#pragma unroll
    for (int nt = 0; nt < 2; nt++) {
      size_t off = ((size_t)b * N_ + n0 + nt * 16 + n16) * C_ + kk * 32 + quad * 8;
      Ah[nt] = *(const bf16x8f*)(const void*)(xthi + off);
      Al[nt] = *(const bf16x8f*)(const void*)(xtlo + off);
    }
#pragma unroll
    for (int ct = 0; ct < 2; ct++) {
      size_t off = ((size_t)b * C_ + c0 + ct * 16 + n16) * C_ + kk * 32 + quad * 8;
      Bh[ct] = *(const bf16x8f*)(const void*)(ahi + off);
      Bl[ct] = *(const bf16x8f*)(const void*)(alo + off);
    }
#pragma unroll
    for (int nt = 0; nt < 2; nt++)
#pragma unroll
      for (int ct = 0; ct < 2; ct++) {
        acc[nt][ct] = __builtin_amdgcn_mfma_f32_16x16x32_bf16(Ah[nt], Bh[ct], acc[nt][ct], 0, 0, 0);
        acc[nt][ct] = __builtin_amdgcn_mfma_f32_16x16x32_bf16(Al[nt], Bh[ct], acc[nt][ct], 0, 0, 0);
        acc[nt][ct] = __builtin_amdgcn_mfma_f32_16x16x32_bf16(Ah[nt], Bl[ct], acc[nt][ct], 0, 0, 0);
      }
  }
  float gp = gpam[0], gc = gcam[0];
#pragma unroll
  for (int nt = 0; nt < 2; nt++)
#pragma unroll
    for (int ct = 0; ct < 2; ct++) {
      int c = c0 + ct * 16 + n16;
      int nb = n0 + nt * 16 + quad * 4;
      const float* xp = x + ((size_t)b * C_ + c) * N_ + nb;
      float4 x4 = *(const float4*)(const void*)xp;
      float4 o4;
      o4.x = gp * pamT[((size_t)b * N_ + nb + 0) * C_ + c] + gc * acc[nt][ct][0] + 2.0f * x4.x;
      o4.y = gp * pamT[((size_t)b * N_ + nb + 1) * C_ + c] + gc * acc[nt][ct][1] + 2.0f * x4.y;
      o4.z = gp * pamT[((size_t)b * N_ + nb + 2) * C_ + c] + gc * acc[nt][ct][2] + 2.0f * x4.z;
      o4.w = gp * pamT[((size_t)b * N_ + nb + 3) * C_ + c] + gc * acc[nt][ct][3] + 2.0f * x4.w;
      *(float4*)(out + ((size_t)b * C_ + c) * N_ + nb) = o4;
    }
}

extern "C" void kernel_launch(void* const* d_in, const int* in_sizes, int n_in,
                              void* d_out, int out_size, void* d_ws, size_t ws_size,
                              hipStream_t stream) {
  const float* x  = (const float*)d_in[0];
  const float* wq = (const float*)d_in[1];
  const float* bq = (const float*)d_in[2];
  const float* wk = (const float*)d_in[3];
  const float* bk = (const float*)d_in[4];
  const float* wv = (const float*)d_in[5];
  const float* bv = (const float*)d_in[6];
  const float* gp = (const float*)d_in[7];
  const float* gc = (const float*)d_in[8];
  float* out = (float*)d_out;

  float* ws = (float*)d_ws;
  size_t o = 0;
  float* pamT  = ws + o; o += (size_t)B_ * N_ * C_;     // 2097152
  float* mp    = ws + o; o += (size_t)2 * B_ * N_;      // 16384
  float* lp    = ws + o; o += (size_t)2 * B_ * N_;      // 16384
  float* eCp   = ws + o; o += (size_t)8 * B_ * C_ * C_; // 1048576
  bf16*  ahi   = (bf16*)(ws + o); o += (size_t)B_ * C_ * C_ / 2;   // 65536 fl
  bf16*  alo   = (bf16*)(ws + o); o += (size_t)B_ * C_ * C_ / 2;   // 65536 fl
  bf16*  vbf   = (bf16*)(ws + o); o += (size_t)B_ * N_ * C_ / 2;   // 1048576
  bf16*  qhi   = (bf16*)(ws + o); o += (size_t)B_ * N_ * QK_ / 2;  // 131072
  bf16*  qlo   = (bf16*)(ws + o); o += (size_t)B_ * N_ * QK_ / 2;  // 131072
  bf16*  khi   = (bf16*)(ws + o); o += (size_t)B_ * N_ * QK_ / 2;  // 131072
  bf16*  klo   = (bf16*)(ws + o); o += (size_t)B_ * N_ * QK_ / 2;  // 131072
  float* xtbuf = ws + o; o += (size_t)2 * B_ * N_ * QK_ * 4;       // 2097152 (xT hi/lo)
  // xT hi/lo occupy the former qpprt/kpprt region (2 x 1M floats)
  bf16* xthi = (bf16*)xtbuf;
  bf16* xtlo = (bf16*)(xtbuf + (size_t)B_ * N_ * C_ / 2);
  // weight hi/lo buffers alias eCp (dead until k_ce; k_vbf2/k_qkp run first)
  bf16* wqkh = (bf16*)eCp;
  bf16* wqkl = wqkh + (size_t)64 * C_;
  bf16* wvh  = wqkl + (size_t)64 * C_;
  bf16* wvl  = wvh + (size_t)C_ * C_;
  // total ~6.8 M floats = 27.4 MB (unchanged)

  k_wcv<<<dim3((64 * C_ + C_ * C_) / 256), dim3(256), 0, stream>>>(wq, wk, wv, wqkh, wqkl, wvh, wvl);
  k_xt<<<dim3(N_ / 64, C_ / 64, B_), dim3(256), 0, stream>>>(x, xthi, xtlo);
  k_qkp<<<dim3(N_ / 128, B_), dim3(256), 0, stream>>>(xthi, xtlo, wqkh, wqkl, bq, bk, qhi, qlo, khi, klo);
  k_vbf2<<<dim3(N_ / 32, B_), dim3(256), 0, stream>>>(xthi, xtlo, wvh, wvl, bv, vbf);
  k_pam2<<<dim3(N_ / 64, 2, B_), dim3(512), 0, stream>>>(qhi, qlo, khi, klo, mp, lp);
  k_pbm<<<dim3(N_ / 64, 2, B_), dim3(512), 0, stream>>>(qhi, qlo, khi, klo, vbf, mp, lp, pamT);
  k_ce<<<dim3(64, 8, B_), dim3(256), 0, stream>>>(x, eCp);
  k_cs<<<dim3(B_ * C_), dim3(256), 0, stream>>>(eCp, ahi, alo);
  k_cam<<<dim3(N_ / 32, B_), dim3(512), 0, stream>>>(xthi, xtlo, ahi, alo, pamT, x, gp, gc, out);
}